// Round 6
// baseline (1258.157 us; speedup 1.0000x reference)
//
#include <hip/hip_runtime.h>
#include <stdint.h>
#include <math.h>

#define NN   100000
#define FIN  128
#define HIDDEN 256
#define NCLS 40
#define NE   1600000

// CSR bucketing: P node-ranges x S edge-slices
#define PRNG 8
#define RNG  12500          // NN / PRNG
#define SSL  32
#define NES  50000          // NE / SSL

typedef unsigned short u16;
typedef __attribute__((ext_vector_type(8))) short s16x8;
typedef __attribute__((ext_vector_type(4))) float f32x4;

__device__ __forceinline__ float bf2f(unsigned short u) {
    union { float f; uint32_t i; } v; v.i = ((uint32_t)u) << 16; return v.f;
}
__device__ __forceinline__ unsigned short f2bf(float f) {
    union { float f; uint32_t i; } v; v.f = f;
    uint32_t r = v.i + 0x7fffu + ((v.i >> 16) & 1u);
    return (unsigned short)(r >> 16);
}

// ---------------- dtype detection ----------------
__global__ void k_detect(const u16* __restrict__ x16, const int* __restrict__ ei,
                         int* __restrict__ flags) {
    int t = threadIdx.x;
    int nan_cnt = 0;
    for (int i = t; i < 65536; i += 256) {
        u16 v = x16[i] & 0x7fff;
        if (v >= 0x7f80) nan_cnt++;
    }
    int odd_nz = 0;
    for (int i = t; i < 8192; i += 256) {
        if (ei[2 * i + 1] != 0) odd_nz++;
    }
    if (nan_cnt) atomicAdd(&flags[0], nan_cnt);
    if (odd_nz) atomicAdd(&flags[2], 1);
}

__global__ void k_finalize_flags(int* flags) {
    if (threadIdx.x == 0 && blockIdx.x == 0) flags[1] = (flags[2] == 0) ? 1 : 0;
}

__global__ void k_cvt(const void* __restrict__ src, u16* __restrict__ dst, int n,
                      const int* __restrict__ flags) {
    int i = blockIdx.x * 256 + threadIdx.x;
    if (i >= n) return;
    if (flags[0]) dst[i] = f2bf(((const float*)src)[i]);
    else          dst[i] = ((const u16*)src)[i];
}

__global__ void k_cvt_bias(const void* b1, const void* b2, const void* b3, const void* b4,
                           u16* o1, u16* o2, u16* o3, u16* o4,
                           const int* __restrict__ flags) {
    int t = threadIdx.x;
    int fl = flags[0];
    o1[t] = fl ? f2bf(((const float*)b1)[t]) : ((const u16*)b1)[t];
    o2[t] = fl ? f2bf(((const float*)b2)[t]) : ((const u16*)b2)[t];
    o3[t] = fl ? f2bf(((const float*)b3)[t]) : ((const u16*)b3)[t];
    if (t < NCLS) o4[t] = fl ? f2bf(((const float*)b4)[t]) : ((const u16*)b4)[t];
}

__global__ void k_transpose_all(const void* W1, const void* W2, const void* W3, const void* W4,
                                u16* W1t, u16* W2t, u16* W3t, u16* W4t,
                                const int* __restrict__ flags) {
    int b = blockIdx.x;
    const void* W; u16* Wt; int K, F, Fpad, base;
    if (b < 128)      { W = W1; Wt = W1t; K = 128; F = 256; Fpad = 256; base = 0; }
    else if (b < 384) { W = W2; Wt = W2t; K = 256; F = 256; Fpad = 256; base = 128; }
    else if (b < 640) { W = W3; Wt = W3t; K = 256; F = 256; Fpad = 256; base = 384; }
    else              { W = W4; Wt = W4t; K = 256; F = 40;  Fpad = 64;  base = 640; }
    int idx = (b - base) * 256 + threadIdx.x;
    if (idx >= K * Fpad) return;
    int f = idx / K, k = idx - f * K;
    u16 v = 0;
    if (f < F) {
        if (flags[0]) v = f2bf(((const float*)W)[(size_t)k * F + f]);
        else          v = ((const u16*)W)[(size_t)k * F + f];
    }
    Wt[idx] = v;
}

// ---------------- CSR build (no device atomics; reads edge_index directly) ----------------

__global__ __launch_bounds__(256) void k_histb(const int* __restrict__ ei,
                                               int* __restrict__ partial,
                                               const int* __restrict__ flags) {
    __shared__ int h[RNG];
    int p = blockIdx.x >> 5, s = blockIdx.x & 31;
    int t = threadIdx.x;
    int4 z4 = make_int4(0, 0, 0, 0);
    for (int i = t * 4; i < RNG; i += 1024) *(int4*)(h + i) = z4;
    __syncthreads();
    int base = s * NES;
    int lo = p * RNG;
    int nfull = NES & ~1023;
    if (flags[1]) {  // int64: dst at ei[2*(NE+e)], take even dwords
        const int* d = ei + 2 * (size_t)NE;
        for (int k = t * 4; k < nfull; k += 1024) {
            int4 q0 = *(const int4*)(d + 2 * (base + k));
            int4 q1 = *(const int4*)(d + 2 * (base + k) + 4);
            int a;
            a = q0.x - lo; if ((unsigned)a < RNG) atomicAdd(&h[a], 1);
            a = q0.z - lo; if ((unsigned)a < RNG) atomicAdd(&h[a], 1);
            a = q1.x - lo; if ((unsigned)a < RNG) atomicAdd(&h[a], 1);
            a = q1.z - lo; if ((unsigned)a < RNG) atomicAdd(&h[a], 1);
        }
        for (int k = nfull + t; k < NES; k += 256) {
            int a = d[2 * (base + k)] - lo;
            if ((unsigned)a < RNG) atomicAdd(&h[a], 1);
        }
    } else {
        const int* d = ei + NE;
        for (int k = t * 4; k < nfull; k += 1024) {
            int4 d4 = *(const int4*)(d + base + k);
            int a;
            a = d4.x - lo; if ((unsigned)a < RNG) atomicAdd(&h[a], 1);
            a = d4.y - lo; if ((unsigned)a < RNG) atomicAdd(&h[a], 1);
            a = d4.z - lo; if ((unsigned)a < RNG) atomicAdd(&h[a], 1);
            a = d4.w - lo; if ((unsigned)a < RNG) atomicAdd(&h[a], 1);
        }
        for (int k = nfull + t; k < NES; k += 256) {
            int a = d[base + k] - lo;
            if ((unsigned)a < RNG) atomicAdd(&h[a], 1);
        }
    }
    __syncthreads();
    int* out = partial + blockIdx.x * RNG;
    for (int i = t * 4; i < RNG; i += 1024) *(int4*)(out + i) = *(const int4*)(h + i);
}

__global__ void k_sumpart(const int* __restrict__ partial, int* __restrict__ cnt) {
    int i = blockIdx.x * 256 + threadIdx.x;
    if (i >= NN) return;
    int p = i / RNG, il = i - p * RNG;
    const int* q = partial + (p * SSL) * RNG + il;
    int sum = 0;
#pragma unroll
    for (int s = 0; s < SSL; ++s) sum += q[s * RNG];
    cnt[i] = sum;
}

__global__ __launch_bounds__(256) void k_scan1(const int* __restrict__ cnt,
                                               int* __restrict__ out,
                                               int* __restrict__ bsum) {
    __shared__ int sh[256];
    int t = threadIdx.x;
    int base = blockIdx.x * 1024 + t * 4;
    int v0 = 0, v1 = 0, v2 = 0, v3 = 0;
    if (base + 0 < NN) v0 = cnt[base + 0];
    if (base + 1 < NN) v1 = cnt[base + 1];
    if (base + 2 < NN) v2 = cnt[base + 2];
    if (base + 3 < NN) v3 = cnt[base + 3];
    int s = v0 + v1 + v2 + v3;
    sh[t] = s;
    __syncthreads();
    for (int off = 1; off < 256; off <<= 1) {
        int x = (t >= off) ? sh[t - off] : 0;
        __syncthreads();
        sh[t] += x;
        __syncthreads();
    }
    int ex = sh[t] - s;
    if (base + 0 < NN) out[base + 0] = ex;
    if (base + 1 < NN) out[base + 1] = ex + v0;
    if (base + 2 < NN) out[base + 2] = ex + v0 + v1;
    if (base + 3 < NN) out[base + 3] = ex + v0 + v1 + v2;
    if (t == 255) bsum[blockIdx.x] = sh[255];
}

__global__ void k_scan2(int* bsum, int nb) {
    if (threadIdx.x == 0 && blockIdx.x == 0) {
        int run = 0;
        for (int i = 0; i < nb; ++i) { int t = bsum[i]; bsum[i] = run; run += t; }
    }
}

__global__ void k_scan3(int* __restrict__ rp, const int* __restrict__ bsum,
                        const int* __restrict__ cnt, float* __restrict__ dinv) {
    int i = blockIdx.x * 256 + threadIdx.x;
    if (i < NN) {
        rp[i] = rp[i] + bsum[i >> 10];
        dinv[i] = rsqrtf((float)(cnt[i] + 1));
    }
    if (i == 0) rp[NN] = NE;
}

__global__ void k_offs(int* __restrict__ partial, const int* __restrict__ rp) {
    int i = blockIdx.x * 256 + threadIdx.x;
    if (i >= NN) return;
    int p = i / RNG, il = i - p * RNG;
    int* q = partial + (p * SSL) * RNG + il;
    int run = rp[i];
#pragma unroll
    for (int s = 0; s < SSL; ++s) { int t = q[s * RNG]; q[s * RNG] = run; run += t; }
}

__global__ __launch_bounds__(256) void k_fillb(const int* __restrict__ ei,
                                               const int* __restrict__ offs,
                                               int* __restrict__ col,
                                               const int* __restrict__ flags) {
    __shared__ int h[RNG];
    int p = blockIdx.x >> 5, s = blockIdx.x & 31;
    int t = threadIdx.x;
    const int* o = offs + blockIdx.x * RNG;
    for (int i = t * 4; i < RNG; i += 1024) *(int4*)(h + i) = *(const int4*)(o + i);
    __syncthreads();
    int base = s * NES;
    int lo = p * RNG;
    int nfull = NES & ~1023;
    if (flags[1]) {
        const int* d = ei + 2 * (size_t)NE;
        const int* sp = ei;
        for (int k = t * 4; k < nfull; k += 1024) {
            int4 q0 = *(const int4*)(d + 2 * (base + k));
            int4 q1 = *(const int4*)(d + 2 * (base + k) + 4);
            int4 r0 = *(const int4*)(sp + 2 * (base + k));
            int4 r1 = *(const int4*)(sp + 2 * (base + k) + 4);
            int a;
            a = q0.x - lo; if ((unsigned)a < RNG) col[atomicAdd(&h[a], 1)] = r0.x;
            a = q0.z - lo; if ((unsigned)a < RNG) col[atomicAdd(&h[a], 1)] = r0.z;
            a = q1.x - lo; if ((unsigned)a < RNG) col[atomicAdd(&h[a], 1)] = r1.x;
            a = q1.z - lo; if ((unsigned)a < RNG) col[atomicAdd(&h[a], 1)] = r1.z;
        }
        for (int k = nfull + t; k < NES; k += 256) {
            int a = d[2 * (base + k)] - lo;
            if ((unsigned)a < RNG) col[atomicAdd(&h[a], 1)] = sp[2 * (base + k)];
        }
    } else {
        const int* d = ei + NE;
        const int* sp = ei;
        for (int k = t * 4; k < nfull; k += 1024) {
            int4 d4 = *(const int4*)(d + base + k);
            int4 s4 = *(const int4*)(sp + base + k);
            int a;
            a = d4.x - lo; if ((unsigned)a < RNG) col[atomicAdd(&h[a], 1)] = s4.x;
            a = d4.y - lo; if ((unsigned)a < RNG) col[atomicAdd(&h[a], 1)] = s4.y;
            a = d4.z - lo; if ((unsigned)a < RNG) col[atomicAdd(&h[a], 1)] = s4.z;
            a = d4.w - lo; if ((unsigned)a < RNG) col[atomicAdd(&h[a], 1)] = s4.w;
        }
        for (int k = nfull + t; k < NES; k += 256) {
            int a = d[base + k] - lo;
            if ((unsigned)a < RNG) col[atomicAdd(&h[a], 1)] = sp[base + k];
        }
    }
}

// ---------------- GEMM 128x128 (m97 structure): C = dinv[row]*(A@Wt^T) ----------------

#define GLL(g, l) __builtin_amdgcn_global_load_lds( \
    (const __attribute__((address_space(1))) unsigned int*)(g), \
    (__attribute__((address_space(3))) unsigned int*)(l), 16, 0, 0)

__global__ __launch_bounds__(256) void k_gemm128(const u16* __restrict__ A,
                                                 const u16* __restrict__ Wt,
                                                 const float* __restrict__ dinv,
                                                 u16* __restrict__ C,
                                                 int K) {
    __shared__ __align__(16) u16 As[128 * 32];
    __shared__ __align__(16) u16 Bs[128 * 32];
    int t = threadIdx.x;
    int bm = blockIdx.x, bn = blockIdx.y;
    int rowBase = bm * 128;
    int w = t >> 6, lane = t & 63;
    int wm = w >> 1, wn = w & 1;
    int lrow = lane & 15, lq = lane >> 4;

    f32x4 acc[4][4] = {};

    int r0 = t >> 2;
    int seg = (t & 3) * 8;
    int ar0 = rowBase + r0;       if (ar0 > NN - 1) ar0 = NN - 1;
    int ar1 = rowBase + 64 + r0;  if (ar1 > NN - 1) ar1 = NN - 1;
    const u16* a0p = A + (size_t)ar0 * K + seg;
    const u16* a1p = A + (size_t)ar1 * K + seg;
    const u16* b0p = Wt + (size_t)(bn * 128 + r0) * K + seg;
    const u16* b1p = Wt + (size_t)(bn * 128 + 64 + r0) * K + seg;
    u16* As0 = As + t * 8;
    u16* As1 = As + 2048 + t * 8;
    u16* Bs0 = Bs + t * 8;
    u16* Bs1 = Bs + 2048 + t * 8;

    int nK = K >> 5;
    for (int kt = 0; kt < nK; ++kt) {
        GLL(a0p, As0);
        GLL(a1p, As1);
        GLL(b0p, Bs0);
        GLL(b1p, Bs1);
        a0p += 32; a1p += 32; b0p += 32; b1p += 32;
        __syncthreads();
        s16x8 af[4], bf[4];
#pragma unroll
        for (int i = 0; i < 4; ++i)
            af[i] = *(const s16x8*)(As + (wm * 64 + i * 16 + lrow) * 32 + lq * 8);
#pragma unroll
        for (int j = 0; j < 4; ++j)
            bf[j] = *(const s16x8*)(Bs + (wn * 64 + j * 16 + lrow) * 32 + lq * 8);
#pragma unroll
        for (int i = 0; i < 4; ++i)
#pragma unroll
            for (int j = 0; j < 4; ++j)
                acc[i][j] = __builtin_amdgcn_mfma_f32_16x16x32_bf16(af[i], bf[j], acc[i][j], 0, 0, 0);
        __syncthreads();
    }

#pragma unroll
    for (int i = 0; i < 4; ++i) {
#pragma unroll
        for (int rr = 0; rr < 4; ++rr) {
            int row = rowBase + wm * 64 + i * 16 + lq * 4 + rr;
            if (row < NN) {
                float d = dinv[row];
#pragma unroll
                for (int j = 0; j < 4; ++j) {
                    int colg = bn * 128 + wn * 64 + j * 16 + lrow;
                    C[(size_t)row * HIDDEN + colg] = f2bf(acc[i][j][rr] * d);
                }
            }
        }
    }
}

// ---------------- GEMM 64x64 (conv5) ----------------
#define LDT 40

__global__ __launch_bounds__(256) void k_gemm64(const u16* __restrict__ A,
                                                const u16* __restrict__ Wt,
                                                const float* __restrict__ dinv,
                                                u16* __restrict__ C,
                                                int K, int Fstore) {
    __shared__ __align__(16) u16 As[64 * LDT];
    __shared__ __align__(16) u16 Bs[64 * LDT];
    int t = threadIdx.x;
    int bm = blockIdx.x, bn = blockIdx.y;
    int rowBase = bm * 64;
    int r = t >> 2;
    int cseg = (t & 3) * 8;
    int w = t >> 6;
    int wm = w >> 1, wn = w & 1;
    int lane = t & 63;
    int lrow = lane & 15;
    int lq = lane >> 4;
    f32x4 acc[2][2] = {};

    int nK = K >> 5;
    for (int kt = 0; kt < nK; ++kt) {
        int k0 = kt * 32;
        uint4 av = make_uint4(0, 0, 0, 0);
        int arow = rowBase + r;
        if (arow < NN) av = *(const uint4*)(A + (size_t)arow * K + k0 + cseg);
        *(uint4*)(As + r * LDT + cseg) = av;
        uint4 bv = *(const uint4*)(Wt + (size_t)(bn * 64 + r) * K + k0 + cseg);
        *(uint4*)(Bs + r * LDT + cseg) = bv;
        __syncthreads();

        s16x8 afr[2], bfr[2];
        afr[0] = *(const s16x8*)(As + (wm * 32 + lrow) * LDT + lq * 8);
        afr[1] = *(const s16x8*)(As + (wm * 32 + 16 + lrow) * LDT + lq * 8);
        bfr[0] = *(const s16x8*)(Bs + (wn * 32 + lrow) * LDT + lq * 8);
        bfr[1] = *(const s16x8*)(Bs + (wn * 32 + 16 + lrow) * LDT + lq * 8);
#pragma unroll
        for (int i = 0; i < 2; ++i)
#pragma unroll
            for (int j = 0; j < 2; ++j)
                acc[i][j] = __builtin_amdgcn_mfma_f32_16x16x32_bf16(afr[i], bfr[j], acc[i][j], 0, 0, 0);
        __syncthreads();
    }

#pragma unroll
    for (int ti = 0; ti < 2; ++ti)
#pragma unroll
        for (int tj = 0; tj < 2; ++tj)
#pragma unroll
            for (int rr = 0; rr < 4; ++rr) {
                int row = rowBase + wm * 32 + ti * 16 + lq * 4 + rr;
                int colg = bn * 64 + wn * 32 + tj * 16 + lrow;
                if (row < NN && colg < Fstore)
                    C[(size_t)row * Fstore + colg] = f2bf(acc[ti][tj][rr] * dinv[row]);
            }
}

// ---------------- aggregation F=256, XCD-pinned feature chunks ----------------
// chunk = blockIdx.x & 3 (64 features = 128 B per gather). Under blockIdx%8 -> XCD
// round-robin, each XCD touches only hs[:, chunk*64 .. +64] = 12.8 MB.
// Per wave: 1 row at a time, 4 edge-groups x 16 lanes, each lane 4 features (uint2),
// 2x unrolled (8 edges in flight per wave), then xor-16/32 shuffle reduction.

__global__ __launch_bounds__(256) void k_agg(const u16* __restrict__ hs,
                                             const int* __restrict__ rp,
                                             const int* __restrict__ col,
                                             const float* __restrict__ dinv,
                                             const u16* __restrict__ bias,
                                             u16* __restrict__ out) {
    int w = threadIdx.x >> 6;
    int lane = threadIdx.x & 63;
    int group = lane >> 4;           // 0..3: edge slot
    int fl = lane & 15;              // feature sub-index
    int chunk = blockIdx.x & 3;
    int blk = blockIdx.x >> 2;
    int fb = chunk * 64 + fl * 4;    // element offset within row

    uint2 bv = *(const uint2*)(bias + fb);
    float b0 = bf2f((u16)(bv.x & 0xffff)), b1 = bf2f((u16)(bv.x >> 16));
    float b2 = bf2f((u16)(bv.y & 0xffff)), b3 = bf2f((u16)(bv.y >> 16));

#pragma unroll
    for (int rr = 0; rr < 4; ++rr) {
        int row = blk * 16 + w * 4 + rr;       // NN = 6250*16 exactly
        float a0 = 0.f, a1 = 0.f, a2 = 0.f, a3 = 0.f;
        if (group == 0) {
            uint2 sv = *(const uint2*)(hs + (size_t)row * HIDDEN + fb);
            a0 = bf2f((u16)(sv.x & 0xffff)); a1 = bf2f((u16)(sv.x >> 16));
            a2 = bf2f((u16)(sv.y & 0xffff)); a3 = bf2f((u16)(sv.y >> 16));
        }
        int p = rp[row] + group, p1 = rp[row + 1];
        for (; p + 4 < p1; p += 8) {
            int s0 = col[p], s1 = col[p + 4];
            uint2 v0 = *(const uint2*)(hs + (size_t)s0 * HIDDEN + fb);
            uint2 v1 = *(const uint2*)(hs + (size_t)s1 * HIDDEN + fb);
            a0 += bf2f((u16)(v0.x & 0xffff)); a1 += bf2f((u16)(v0.x >> 16));
            a2 += bf2f((u16)(v0.y & 0xffff)); a3 += bf2f((u16)(v0.y >> 16));
            a0 += bf2f((u16)(v1.x & 0xffff)); a1 += bf2f((u16)(v1.x >> 16));
            a2 += bf2f((u16)(v1.y & 0xffff)); a3 += bf2f((u16)(v1.y >> 16));
        }
        if (p < p1) {
            int s = col[p];
            uint2 v = *(const uint2*)(hs + (size_t)s * HIDDEN + fb);
            a0 += bf2f((u16)(v.x & 0xffff)); a1 += bf2f((u16)(v.x >> 16));
            a2 += bf2f((u16)(v.y & 0xffff)); a3 += bf2f((u16)(v.y >> 16));
        }
        a0 += __shfl_xor(a0, 16); a1 += __shfl_xor(a1, 16);
        a2 += __shfl_xor(a2, 16); a3 += __shfl_xor(a3, 16);
        a0 += __shfl_xor(a0, 32); a1 += __shfl_xor(a1, 32);
        a2 += __shfl_xor(a2, 32); a3 += __shfl_xor(a3, 32);
        if (group == 0) {
            float d = dinv[row];
            float r0 = fmaxf(fmaf(d, a0, b0), 0.f);
            float r1 = fmaxf(fmaf(d, a1, b1), 0.f);
            float r2 = fmaxf(fmaf(d, a2, b2), 0.f);
            float r3 = fmaxf(fmaf(d, a3, b3), 0.f);
            uint2 o;
            o.x = (uint32_t)f2bf(r0) | ((uint32_t)f2bf(r1) << 16);
            o.y = (uint32_t)f2bf(r2) | ((uint32_t)f2bf(r3) << 16);
            *(uint2*)(out + (size_t)row * HIDDEN + fb) = o;
        }
    }
}

// ---------------- last layer: aggregate F=40 + bias + log_softmax ----------------
__global__ __launch_bounds__(256) void k_agg5(const u16* __restrict__ hs,
                                              const int* __restrict__ rp,
                                              const int* __restrict__ col,
                                              const float* __restrict__ dinv,
                                              const u16* __restrict__ bias,
                                              void* __restrict__ out,
                                              const int* __restrict__ flags) {
    int row = blockIdx.x * 4 + (threadIdx.x >> 6);
    if (row >= NN) return;
    int lane = threadIdx.x & 63;
    bool act = lane < NCLS;
    float acc = 0.f;
    if (act) acc = bf2f(hs[(size_t)row * NCLS + lane]);
    int p = rp[row], p1 = rp[row + 1];
    for (; p + 3 < p1; p += 4) {
        int s0 = col[p], s1 = col[p + 1], s2 = col[p + 2], s3 = col[p + 3];
        if (act) {
            float v0 = bf2f(hs[(size_t)s0 * NCLS + lane]);
            float v1 = bf2f(hs[(size_t)s1 * NCLS + lane]);
            float v2 = bf2f(hs[(size_t)s2 * NCLS + lane]);
            float v3 = bf2f(hs[(size_t)s3 * NCLS + lane]);
            acc += (v0 + v1) + (v2 + v3);
        }
    }
    for (; p < p1; ++p) {
        int s = col[p];
        if (act) acc += bf2f(hs[(size_t)s * NCLS + lane]);
    }
    float logit = act ? fmaf(dinv[row], acc, bf2f(bias[lane])) : -1e30f;
    float m = logit;
#pragma unroll
    for (int off = 32; off > 0; off >>= 1) m = fmaxf(m, __shfl_xor(m, off));
    float e = act ? __expf(logit - m) : 0.f;
    float ssum = e;
#pragma unroll
    for (int off = 32; off > 0; off >>= 1) ssum += __shfl_xor(ssum, off);
    if (act) {
        float r = logit - m - __logf(ssum);
        size_t idx = (size_t)row * NCLS + lane;
        if (flags[0]) ((float*)out)[idx] = r;
        else          ((u16*)out)[idx]   = f2bf(r);
    }
}

// ---------------- launch ----------------

extern "C" void kernel_launch(void* const* d_in, const int* in_sizes, int n_in,
                              void* d_out, int out_size, void* d_ws, size_t ws_size,
                              hipStream_t stream) {
    const void* x  = d_in[0];
    const int* ei  = (const int*)d_in[1];
    const void* W1 = d_in[2];
    const void* b1 = d_in[3];
    const void* W2 = d_in[4];
    const void* b2 = d_in[5];
    const void* W3 = d_in[6];
    const void* b3 = d_in[7];
    const void* W4 = d_in[8];
    const void* b4 = d_in[9];

    char* p = (char*)d_ws;
    auto alloc = [&](size_t b) -> char* {
        char* r = p;
        p += (b + 255) & ~(size_t)255;
        return r;
    };
    int*   flags = (int*)alloc(256);
    int*   cnt  = (int*)alloc((size_t)NN * 4);
    float* dinv = (float*)alloc((size_t)NN * 4);
    int*   rp   = (int*)alloc((size_t)(NN + 1) * 4);
    int*   col  = (int*)alloc((size_t)NE * 4);
    int*   bsum = (int*)alloc(4096);
    u16* xb  = (u16*)alloc((size_t)NN * FIN * 2);
    u16* W1t = (u16*)alloc((size_t)256 * 128 * 2);
    u16* W2t = (u16*)alloc((size_t)256 * 256 * 2);
    u16* W3t = (u16*)alloc((size_t)256 * 256 * 2);
    u16* W4t = (u16*)alloc((size_t)64 * 256 * 2);
    u16* bb1 = (u16*)alloc(512);
    u16* bb2 = (u16*)alloc(512);
    u16* bb3 = (u16*)alloc(512);
    u16* bb4 = (u16*)alloc(128);
    u16* bufA = (u16*)alloc((size_t)NN * HIDDEN * 2);
    u16* bufB = (u16*)alloc((size_t)NN * HIDDEN * 2);

    // CSR-build scratch aliased into bufB (used strictly before any conv)
    int* partial = (int*)bufB;                    // PRNG*SSL*RNG*4 = 12.8 MB

    hipMemsetAsync(flags, 0, 256, stream);
    k_detect<<<1, 256, 0, stream>>>((const u16*)x, ei, flags);
    k_finalize_flags<<<1, 64, 0, stream>>>(flags);

    // CSR build (atomic-free at device scope)
    k_histb<<<PRNG * SSL, 256, 0, stream>>>(ei, partial, flags);
    k_sumpart<<<(NN + 255) / 256, 256, 0, stream>>>(partial, cnt);
    k_scan1<<<(NN + 1023) / 1024, 256, 0, stream>>>(cnt, rp, bsum);
    k_scan2<<<1, 64, 0, stream>>>(bsum, (NN + 1023) / 1024);
    k_scan3<<<(NN + 255) / 256, 256, 0, stream>>>(rp, bsum, cnt, dinv);
    k_offs<<<(NN + 255) / 256, 256, 0, stream>>>(partial, rp);
    k_fillb<<<PRNG * SSL, 256, 0, stream>>>(ei, partial, col, flags);

    // weights / inputs to bf16
    k_cvt<<<(NN * FIN + 255) / 256, 256, 0, stream>>>(x, xb, NN * FIN, flags);
    k_cvt_bias<<<1, 256, 0, stream>>>(b1, b2, b3, b4, bb1, bb2, bb3, bb4, flags);
    k_transpose_all<<<704, 256, 0, stream>>>(W1, W2, W3, W4, W1t, W2t, W3t, W4t, flags);

    dim3 g128((NN + 127) / 128, 2);
    dim3 aggGrid(((NN + 15) / 16) * 4);   // 4 feature chunks x 6250 row-blocks
    dim3 agg5Grid((NN + 3) / 4);

    // conv1: x @ W1 (K=128)
    k_gemm128<<<g128, 256, 0, stream>>>(xb, W1t, dinv, bufB, 128);
    k_agg<<<aggGrid, 256, 0, stream>>>(bufB, rp, col, dinv, bb1, bufA);
    // conv2: @ W2
    k_gemm128<<<g128, 256, 0, stream>>>(bufA, W2t, dinv, bufB, 256);
    k_agg<<<aggGrid, 256, 0, stream>>>(bufB, rp, col, dinv, bb2, bufA);
    // conv3: @ W2 (reused)
    k_gemm128<<<g128, 256, 0, stream>>>(bufA, W2t, dinv, bufB, 256);
    k_agg<<<aggGrid, 256, 0, stream>>>(bufB, rp, col, dinv, bb2, bufA);
    // conv4: @ W3
    k_gemm128<<<g128, 256, 0, stream>>>(bufA, W3t, dinv, bufB, 256);
    k_agg<<<aggGrid, 256, 0, stream>>>(bufB, rp, col, dinv, bb3, bufA);
    // conv5: @ W4 (Fpad=64, store 40) + fused log_softmax
    dim3 g64((NN + 63) / 64, 1);
    k_gemm64<<<g64, 256, 0, stream>>>(bufA, W4t, dinv, bufB, 256, 40);
    k_agg5<<<agg5Grid, 256, 0, stream>>>(bufB, rp, col, dinv, bb4, d_out, flags);
}

// Round 7
// 993.738 us; speedup vs baseline: 1.2661x; 1.2661x over previous
//
#include <hip/hip_runtime.h>
#include <stdint.h>
#include <math.h>

#define NN   100000
#define FIN  128
#define HIDDEN 256
#define NCLS 40
#define NE   1600000

// CSR bucketing: P node-ranges x S edge-slices
#define PRNG 8
#define RNG  12500          // NN / PRNG
#define SSL  32
#define NES  50000          // NE / SSL

typedef unsigned short u16;
typedef __attribute__((ext_vector_type(8))) short s16x8;
typedef __attribute__((ext_vector_type(4))) float f32x4;

__device__ __forceinline__ float bf2f(unsigned short u) {
    union { float f; uint32_t i; } v; v.i = ((uint32_t)u) << 16; return v.f;
}
__device__ __forceinline__ unsigned short f2bf(float f) {
    union { float f; uint32_t i; } v; v.f = f;
    uint32_t r = v.i + 0x7fffu + ((v.i >> 16) & 1u);
    return (unsigned short)(r >> 16);
}

// ---------------- dtype detection (single block, self-contained) ----------------
// flags[0] != 0 => float tensors are float32 (else bf16); flags[1] != 0 => edge_index int64
__global__ void k_detect(const u16* __restrict__ x16, const int* __restrict__ ei,
                         int* __restrict__ flags) {
    __shared__ int sh_nan, sh_odd;
    if (threadIdx.x == 0) { sh_nan = 0; sh_odd = 0; }
    __syncthreads();
    int t = threadIdx.x;
    int nan_cnt = 0;
    for (int i = t; i < 65536; i += 256) {
        u16 v = x16[i] & 0x7fff;
        if (v >= 0x7f80) nan_cnt++;
    }
    int odd_nz = 0;
    for (int i = t; i < 8192; i += 256) {
        if (ei[2 * i + 1] != 0) odd_nz++;
    }
    if (nan_cnt) atomicAdd(&sh_nan, nan_cnt);
    if (odd_nz) atomicAdd(&sh_odd, 1);
    __syncthreads();
    if (threadIdx.x == 0) {
        flags[0] = sh_nan;
        flags[1] = (sh_odd == 0) ? 1 : 0;
    }
}

__global__ void k_cvt(const void* __restrict__ src, u16* __restrict__ dst, int n,
                      const int* __restrict__ flags) {
    int i = blockIdx.x * 256 + threadIdx.x;
    if (i >= n) return;
    if (flags[0]) dst[i] = f2bf(((const float*)src)[i]);
    else          dst[i] = ((const u16*)src)[i];
}

__global__ void k_cvt_bias(const void* b1, const void* b2, const void* b3, const void* b4,
                           u16* o1, u16* o2, u16* o3, u16* o4,
                           const int* __restrict__ flags) {
    int t = threadIdx.x;
    int fl = flags[0];
    o1[t] = fl ? f2bf(((const float*)b1)[t]) : ((const u16*)b1)[t];
    o2[t] = fl ? f2bf(((const float*)b2)[t]) : ((const u16*)b2)[t];
    o3[t] = fl ? f2bf(((const float*)b3)[t]) : ((const u16*)b3)[t];
    if (t < 64) o4[t] = (t < NCLS) ? (fl ? f2bf(((const float*)b4)[t]) : ((const u16*)b4)[t]) : (u16)0;
}

__global__ void k_transpose_all(const void* W1, const void* W2, const void* W3, const void* W4,
                                u16* W1t, u16* W2t, u16* W3t, u16* W4t,
                                const int* __restrict__ flags) {
    int b = blockIdx.x;
    const void* W; u16* Wt; int K, F, Fpad, base;
    if (b < 128)      { W = W1; Wt = W1t; K = 128; F = 256; Fpad = 256; base = 0; }
    else if (b < 384) { W = W2; Wt = W2t; K = 256; F = 256; Fpad = 256; base = 128; }
    else if (b < 640) { W = W3; Wt = W3t; K = 256; F = 256; Fpad = 256; base = 384; }
    else              { W = W4; Wt = W4t; K = 256; F = 40;  Fpad = 64;  base = 640; }
    int idx = (b - base) * 256 + threadIdx.x;
    if (idx >= K * Fpad) return;
    int f = idx / K, k = idx - f * K;
    u16 v = 0;
    if (f < F) {
        if (flags[0]) v = f2bf(((const float*)W)[(size_t)k * F + f]);
        else          v = ((const u16*)W)[(size_t)k * F + f];
    }
    Wt[idx] = v;
}

// ---------------- CSR build (no device atomics; reads edge_index directly) ----------------

__global__ __launch_bounds__(256) void k_histb(const int* __restrict__ ei,
                                               int* __restrict__ partial,
                                               const int* __restrict__ flags) {
    __shared__ int h[RNG];
    int p = blockIdx.x >> 5, s = blockIdx.x & 31;
    int t = threadIdx.x;
    int4 z4 = make_int4(0, 0, 0, 0);
    for (int i = t * 4; i < RNG; i += 1024) *(int4*)(h + i) = z4;
    __syncthreads();
    int base = s * NES;
    int lo = p * RNG;
    int nfull = NES & ~1023;
    if (flags[1]) {  // int64: dst at ei[2*(NE+e)], take even dwords
        const int* d = ei + 2 * (size_t)NE;
        for (int k = t * 4; k < nfull; k += 1024) {
            int4 q0 = *(const int4*)(d + 2 * (base + k));
            int4 q1 = *(const int4*)(d + 2 * (base + k) + 4);
            int a;
            a = q0.x - lo; if ((unsigned)a < RNG) atomicAdd(&h[a], 1);
            a = q0.z - lo; if ((unsigned)a < RNG) atomicAdd(&h[a], 1);
            a = q1.x - lo; if ((unsigned)a < RNG) atomicAdd(&h[a], 1);
            a = q1.z - lo; if ((unsigned)a < RNG) atomicAdd(&h[a], 1);
        }
        for (int k = nfull + t; k < NES; k += 256) {
            int a = d[2 * (base + k)] - lo;
            if ((unsigned)a < RNG) atomicAdd(&h[a], 1);
        }
    } else {
        const int* d = ei + NE;
        for (int k = t * 4; k < nfull; k += 1024) {
            int4 d4 = *(const int4*)(d + base + k);
            int a;
            a = d4.x - lo; if ((unsigned)a < RNG) atomicAdd(&h[a], 1);
            a = d4.y - lo; if ((unsigned)a < RNG) atomicAdd(&h[a], 1);
            a = d4.z - lo; if ((unsigned)a < RNG) atomicAdd(&h[a], 1);
            a = d4.w - lo; if ((unsigned)a < RNG) atomicAdd(&h[a], 1);
        }
        for (int k = nfull + t; k < NES; k += 256) {
            int a = d[base + k] - lo;
            if ((unsigned)a < RNG) atomicAdd(&h[a], 1);
        }
    }
    __syncthreads();
    int* out = partial + blockIdx.x * RNG;
    for (int i = t * 4; i < RNG; i += 1024) *(int4*)(out + i) = *(const int4*)(h + i);
}

__global__ void k_sumpart(const int* __restrict__ partial, int* __restrict__ cnt) {
    int i = blockIdx.x * 256 + threadIdx.x;
    if (i >= NN) return;
    int p = i / RNG, il = i - p * RNG;
    const int* q = partial + (p * SSL) * RNG + il;
    int sum = 0;
#pragma unroll
    for (int s = 0; s < SSL; ++s) sum += q[s * RNG];
    cnt[i] = sum;
}

__global__ __launch_bounds__(256) void k_scan1(const int* __restrict__ cnt,
                                               int* __restrict__ out,
                                               int* __restrict__ bsum) {
    __shared__ int sh[256];
    int t = threadIdx.x;
    int base = blockIdx.x * 1024 + t * 4;
    int v0 = 0, v1 = 0, v2 = 0, v3 = 0;
    if (base + 0 < NN) v0 = cnt[base + 0];
    if (base + 1 < NN) v1 = cnt[base + 1];
    if (base + 2 < NN) v2 = cnt[base + 2];
    if (base + 3 < NN) v3 = cnt[base + 3];
    int s = v0 + v1 + v2 + v3;
    sh[t] = s;
    __syncthreads();
    for (int off = 1; off < 256; off <<= 1) {
        int x = (t >= off) ? sh[t - off] : 0;
        __syncthreads();
        sh[t] += x;
        __syncthreads();
    }
    int ex = sh[t] - s;
    if (base + 0 < NN) out[base + 0] = ex;
    if (base + 1 < NN) out[base + 1] = ex + v0;
    if (base + 2 < NN) out[base + 2] = ex + v0 + v1;
    if (base + 3 < NN) out[base + 3] = ex + v0 + v1 + v2;
    if (t == 255) bsum[blockIdx.x] = sh[255];
}

__global__ void k_scan2(int* bsum, int nb) {
    if (threadIdx.x == 0 && blockIdx.x == 0) {
        int run = 0;
        for (int i = 0; i < nb; ++i) { int t = bsum[i]; bsum[i] = run; run += t; }
    }
}

// finalize rp, dinv, and convert partial -> absolute slice offsets (fused old scan3+offs)
__global__ void k_scan3o(int* __restrict__ rp, const int* __restrict__ bsum,
                         const int* __restrict__ cnt, float* __restrict__ dinv,
                         int* __restrict__ partial) {
    int i = blockIdx.x * 256 + threadIdx.x;
    if (i < NN) {
        int v = rp[i] + bsum[i >> 10];
        rp[i] = v;
        dinv[i] = rsqrtf((float)(cnt[i] + 1));
        int p = i / RNG, il = i - p * RNG;
        int* q = partial + (p * SSL) * RNG + il;
        int run = v;
#pragma unroll
        for (int s = 0; s < SSL; ++s) { int t = q[s * RNG]; q[s * RNG] = run; run += t; }
    }
    if (i == 0) rp[NN] = NE;
}

__global__ __launch_bounds__(256) void k_fillb(const int* __restrict__ ei,
                                               const int* __restrict__ offs,
                                               int* __restrict__ col,
                                               const int* __restrict__ flags) {
    __shared__ int h[RNG];
    int p = blockIdx.x >> 5, s = blockIdx.x & 31;
    int t = threadIdx.x;
    const int* o = offs + blockIdx.x * RNG;
    for (int i = t * 4; i < RNG; i += 1024) *(int4*)(h + i) = *(const int4*)(o + i);
    __syncthreads();
    int base = s * NES;
    int lo = p * RNG;
    int nfull = NES & ~1023;
    if (flags[1]) {
        const int* d = ei + 2 * (size_t)NE;
        const int* sp = ei;
        for (int k = t * 4; k < nfull; k += 1024) {
            int4 q0 = *(const int4*)(d + 2 * (base + k));
            int4 q1 = *(const int4*)(d + 2 * (base + k) + 4);
            int4 r0 = *(const int4*)(sp + 2 * (base + k));
            int4 r1 = *(const int4*)(sp + 2 * (base + k) + 4);
            int a;
            a = q0.x - lo; if ((unsigned)a < RNG) col[atomicAdd(&h[a], 1)] = r0.x;
            a = q0.z - lo; if ((unsigned)a < RNG) col[atomicAdd(&h[a], 1)] = r0.z;
            a = q1.x - lo; if ((unsigned)a < RNG) col[atomicAdd(&h[a], 1)] = r1.x;
            a = q1.z - lo; if ((unsigned)a < RNG) col[atomicAdd(&h[a], 1)] = r1.z;
        }
        for (int k = nfull + t; k < NES; k += 256) {
            int a = d[2 * (base + k)] - lo;
            if ((unsigned)a < RNG) col[atomicAdd(&h[a], 1)] = sp[2 * (base + k)];
        }
    } else {
        const int* d = ei + NE;
        const int* sp = ei;
        for (int k = t * 4; k < nfull; k += 1024) {
            int4 d4 = *(const int4*)(d + base + k);
            int4 s4 = *(const int4*)(sp + base + k);
            int a;
            a = d4.x - lo; if ((unsigned)a < RNG) col[atomicAdd(&h[a], 1)] = s4.x;
            a = d4.y - lo; if ((unsigned)a < RNG) col[atomicAdd(&h[a], 1)] = s4.y;
            a = d4.z - lo; if ((unsigned)a < RNG) col[atomicAdd(&h[a], 1)] = s4.z;
            a = d4.w - lo; if ((unsigned)a < RNG) col[atomicAdd(&h[a], 1)] = s4.w;
        }
        for (int k = nfull + t; k < NES; k += 256) {
            int a = d[base + k] - lo;
            if ((unsigned)a < RNG) col[atomicAdd(&h[a], 1)] = sp[base + k];
        }
    }
}

// ---------------- GEMM 128x128 (m97 structure): C = dinv[row]*(A@Wt^T) ----------------

#define GLL(g, l) __builtin_amdgcn_global_load_lds( \
    (const __attribute__((address_space(1))) unsigned int*)(g), \
    (__attribute__((address_space(3))) unsigned int*)(l), 16, 0, 0)

__global__ __launch_bounds__(256) void k_gemm128(const u16* __restrict__ A,
                                                 const u16* __restrict__ Wt,
                                                 const float* __restrict__ dinv,
                                                 u16* __restrict__ C,
                                                 int K) {
    __shared__ __align__(16) u16 As[128 * 32];
    __shared__ __align__(16) u16 Bs[128 * 32];
    int t = threadIdx.x;
    int bm = blockIdx.x, bn = blockIdx.y;
    int rowBase = bm * 128;
    int w = t >> 6, lane = t & 63;
    int wm = w >> 1, wn = w & 1;
    int lrow = lane & 15, lq = lane >> 4;

    f32x4 acc[4][4] = {};

    int r0 = t >> 2;
    int seg = (t & 3) * 8;
    int ar0 = rowBase + r0;       if (ar0 > NN - 1) ar0 = NN - 1;
    int ar1 = rowBase + 64 + r0;  if (ar1 > NN - 1) ar1 = NN - 1;
    const u16* a0p = A + (size_t)ar0 * K + seg;
    const u16* a1p = A + (size_t)ar1 * K + seg;
    const u16* b0p = Wt + (size_t)(bn * 128 + r0) * K + seg;
    const u16* b1p = Wt + (size_t)(bn * 128 + 64 + r0) * K + seg;
    u16* As0 = As + t * 8;
    u16* As1 = As + 2048 + t * 8;
    u16* Bs0 = Bs + t * 8;
    u16* Bs1 = Bs + 2048 + t * 8;

    int nK = K >> 5;
    for (int kt = 0; kt < nK; ++kt) {
        GLL(a0p, As0);
        GLL(a1p, As1);
        GLL(b0p, Bs0);
        GLL(b1p, Bs1);
        a0p += 32; a1p += 32; b0p += 32; b1p += 32;
        __syncthreads();
        s16x8 af[4], bf[4];
#pragma unroll
        for (int i = 0; i < 4; ++i)
            af[i] = *(const s16x8*)(As + (wm * 64 + i * 16 + lrow) * 32 + lq * 8);
#pragma unroll
        for (int j = 0; j < 4; ++j)
            bf[j] = *(const s16x8*)(Bs + (wn * 64 + j * 16 + lrow) * 32 + lq * 8);
#pragma unroll
        for (int i = 0; i < 4; ++i)
#pragma unroll
            for (int j = 0; j < 4; ++j)
                acc[i][j] = __builtin_amdgcn_mfma_f32_16x16x32_bf16(af[i], bf[j], acc[i][j], 0, 0, 0);
        __syncthreads();
    }

#pragma unroll
    for (int i = 0; i < 4; ++i) {
#pragma unroll
        for (int rr = 0; rr < 4; ++rr) {
            int row = rowBase + wm * 64 + i * 16 + lq * 4 + rr;
            if (row < NN) {
                float d = dinv[row];
#pragma unroll
                for (int j = 0; j < 4; ++j) {
                    int colg = bn * 128 + wn * 64 + j * 16 + lrow;
                    C[(size_t)row * HIDDEN + colg] = f2bf(acc[i][j][rr] * d);
                }
            }
        }
    }
}

// ---------------- GEMM 64x64 (conv5) ----------------
#define LDT 40

__global__ __launch_bounds__(256) void k_gemm64(const u16* __restrict__ A,
                                                const u16* __restrict__ Wt,
                                                const float* __restrict__ dinv,
                                                u16* __restrict__ C,
                                                int K, int Fstore) {
    __shared__ __align__(16) u16 As[64 * LDT];
    __shared__ __align__(16) u16 Bs[64 * LDT];
    int t = threadIdx.x;
    int bm = blockIdx.x, bn = blockIdx.y;
    int rowBase = bm * 64;
    int r = t >> 2;
    int cseg = (t & 3) * 8;
    int w = t >> 6;
    int wm = w >> 1, wn = w & 1;
    int lane = t & 63;
    int lrow = lane & 15;
    int lq = lane >> 4;
    f32x4 acc[2][2] = {};

    int nK = K >> 5;
    for (int kt = 0; kt < nK; ++kt) {
        int k0 = kt * 32;
        uint4 av = make_uint4(0, 0, 0, 0);
        int arow = rowBase + r;
        if (arow < NN) av = *(const uint4*)(A + (size_t)arow * K + k0 + cseg);
        *(uint4*)(As + r * LDT + cseg) = av;
        uint4 bv = *(const uint4*)(Wt + (size_t)(bn * 64 + r) * K + k0 + cseg);
        *(uint4*)(Bs + r * LDT + cseg) = bv;
        __syncthreads();

        s16x8 afr[2], bfr[2];
        afr[0] = *(const s16x8*)(As + (wm * 32 + lrow) * LDT + lq * 8);
        afr[1] = *(const s16x8*)(As + (wm * 32 + 16 + lrow) * LDT + lq * 8);
        bfr[0] = *(const s16x8*)(Bs + (wn * 32 + lrow) * LDT + lq * 8);
        bfr[1] = *(const s16x8*)(Bs + (wn * 32 + 16 + lrow) * LDT + lq * 8);
#pragma unroll
        for (int i = 0; i < 2; ++i)
#pragma unroll
            for (int j = 0; j < 2; ++j)
                acc[i][j] = __builtin_amdgcn_mfma_f32_16x16x32_bf16(afr[i], bfr[j], acc[i][j], 0, 0, 0);
        __syncthreads();
    }

#pragma unroll
    for (int ti = 0; ti < 2; ++ti)
#pragma unroll
        for (int tj = 0; tj < 2; ++tj)
#pragma unroll
            for (int rr = 0; rr < 4; ++rr) {
                int row = rowBase + wm * 32 + ti * 16 + lq * 4 + rr;
                int colg = bn * 64 + wn * 32 + tj * 16 + lrow;
                if (row < NN && colg < Fstore)
                    C[(size_t)row * Fstore + colg] = f2bf(acc[ti][tj][rr] * dinv[row]);
            }
}

// ---------------- aggregation F=256 (round-4 structure: best measured) ----------------
// one wave per row; half-wave per edge (full 512 B row), 4x unroll (8 gathers in flight)

__device__ __forceinline__ void acc8(float* a, uint4 v) {
    a[0] += bf2f((u16)(v.x & 0xffff)); a[1] += bf2f((u16)(v.x >> 16));
    a[2] += bf2f((u16)(v.y & 0xffff)); a[3] += bf2f((u16)(v.y >> 16));
    a[4] += bf2f((u16)(v.z & 0xffff)); a[5] += bf2f((u16)(v.z >> 16));
    a[6] += bf2f((u16)(v.w & 0xffff)); a[7] += bf2f((u16)(v.w >> 16));
}

__global__ __launch_bounds__(256) void k_agg(const u16* __restrict__ hs,
                                             const int* __restrict__ rp,
                                             const int* __restrict__ col,
                                             const float* __restrict__ dinv,
                                             const u16* __restrict__ bias,
                                             u16* __restrict__ out) {
    int row = blockIdx.x * 4 + (threadIdx.x >> 6);
    if (row >= NN) return;
    int lane = threadIdx.x & 63;
    int half = lane >> 5;
    int fb = (lane & 31) * 8;
    float a[8] = {0.f, 0.f, 0.f, 0.f, 0.f, 0.f, 0.f, 0.f};
    if (half == 0) acc8(a, *(const uint4*)(hs + (size_t)row * HIDDEN + fb));
    int p = rp[row] + half, p1 = rp[row + 1];
    for (; p + 6 < p1; p += 8) {
        int s0 = col[p], s1 = col[p + 2], s2 = col[p + 4], s3 = col[p + 6];
        uint4 v0 = *(const uint4*)(hs + (size_t)s0 * HIDDEN + fb);
        uint4 v1 = *(const uint4*)(hs + (size_t)s1 * HIDDEN + fb);
        uint4 v2 = *(const uint4*)(hs + (size_t)s2 * HIDDEN + fb);
        uint4 v3 = *(const uint4*)(hs + (size_t)s3 * HIDDEN + fb);
        acc8(a, v0);
        acc8(a, v1);
        acc8(a, v2);
        acc8(a, v3);
    }
    for (; p < p1; p += 2) {
        int s = col[p];
        acc8(a, *(const uint4*)(hs + (size_t)s * HIDDEN + fb));
    }
#pragma unroll
    for (int i = 0; i < 8; ++i) a[i] += __shfl_xor(a[i], 32);
    if (half == 0) {
        float d = dinv[row];
        uint4 bv = *(const uint4*)(bias + fb);
        float r0 = fmaxf(fmaf(d, a[0], bf2f((u16)(bv.x & 0xffff))), 0.f);
        float r1 = fmaxf(fmaf(d, a[1], bf2f((u16)(bv.x >> 16))), 0.f);
        float r2 = fmaxf(fmaf(d, a[2], bf2f((u16)(bv.y & 0xffff))), 0.f);
        float r3 = fmaxf(fmaf(d, a[3], bf2f((u16)(bv.y >> 16))), 0.f);
        float r4 = fmaxf(fmaf(d, a[4], bf2f((u16)(bv.z & 0xffff))), 0.f);
        float r5 = fmaxf(fmaf(d, a[5], bf2f((u16)(bv.z >> 16))), 0.f);
        float r6 = fmaxf(fmaf(d, a[6], bf2f((u16)(bv.w & 0xffff))), 0.f);
        float r7 = fmaxf(fmaf(d, a[7], bf2f((u16)(bv.w >> 16))), 0.f);
        uint4 o;
        o.x = (uint32_t)f2bf(r0) | ((uint32_t)f2bf(r1) << 16);
        o.y = (uint32_t)f2bf(r2) | ((uint32_t)f2bf(r3) << 16);
        o.z = (uint32_t)f2bf(r4) | ((uint32_t)f2bf(r5) << 16);
        o.w = (uint32_t)f2bf(r6) | ((uint32_t)f2bf(r7) << 16);
        *(uint4*)(out + (size_t)row * HIDDEN + fb) = o;
    }
}

// ---------------- last layer: hs padded to 64 cols; agg + bias + log_softmax ----------------
// half-wave per edge: 32 lanes x uint (4 B) = full 128 B padded row; 2 classes/lane.
__global__ __launch_bounds__(256) void k_agg5(const u16* __restrict__ hs,
                                              const int* __restrict__ rp,
                                              const int* __restrict__ col,
                                              const float* __restrict__ dinv,
                                              const u16* __restrict__ bias,
                                              void* __restrict__ out,
                                              const int* __restrict__ flags) {
    int row = blockIdx.x * 4 + (threadIdx.x >> 6);
    if (row >= NN) return;
    int lane = threadIdx.x & 63;
    int half = lane >> 5;
    int cl2 = lane & 31;                 // class-pair index (2 classes per lane)
    float a0 = 0.f, a1 = 0.f;
    if (half == 0) {
        uint32_t v = *(const uint32_t*)(hs + (size_t)row * 64 + 2 * cl2);
        a0 = bf2f((u16)(v & 0xffff)); a1 = bf2f((u16)(v >> 16));
    }
    int p = rp[row] + half, p1 = rp[row + 1];
    for (; p + 6 < p1; p += 8) {
        int s0 = col[p], s1 = col[p + 2], s2 = col[p + 4], s3 = col[p + 6];
        uint32_t v0 = *(const uint32_t*)(hs + (size_t)s0 * 64 + 2 * cl2);
        uint32_t v1 = *(const uint32_t*)(hs + (size_t)s1 * 64 + 2 * cl2);
        uint32_t v2 = *(const uint32_t*)(hs + (size_t)s2 * 64 + 2 * cl2);
        uint32_t v3 = *(const uint32_t*)(hs + (size_t)s3 * 64 + 2 * cl2);
        a0 += bf2f((u16)(v0 & 0xffff)) + bf2f((u16)(v1 & 0xffff))
            + bf2f((u16)(v2 & 0xffff)) + bf2f((u16)(v3 & 0xffff));
        a1 += bf2f((u16)(v0 >> 16)) + bf2f((u16)(v1 >> 16))
            + bf2f((u16)(v2 >> 16)) + bf2f((u16)(v3 >> 16));
    }
    for (; p < p1; p += 2) {
        int s = col[p];
        uint32_t v = *(const uint32_t*)(hs + (size_t)s * 64 + 2 * cl2);
        a0 += bf2f((u16)(v & 0xffff));
        a1 += bf2f((u16)(v >> 16));
    }
    a0 += __shfl_xor(a0, 32);
    a1 += __shfl_xor(a1, 32);
    bool act = cl2 < (NCLS / 2);
    float d = dinv[row];
    uint32_t bv = *(const uint32_t*)(bias + 2 * cl2);
    float l0 = act ? fmaf(d, a0, bf2f((u16)(bv & 0xffff))) : -1e30f;
    float l1 = act ? fmaf(d, a1, bf2f((u16)(bv >> 16))) : -1e30f;
    float m = fmaxf(l0, l1);
#pragma unroll
    for (int off = 16; off > 0; off >>= 1) m = fmaxf(m, __shfl_xor(m, off));
    float e = act ? (__expf(l0 - m) + __expf(l1 - m)) : 0.f;
    float ss = e;
#pragma unroll
    for (int off = 16; off > 0; off >>= 1) ss += __shfl_xor(ss, off);
    if (act && half == 0) {
        float lg = __logf(ss);
        float r0 = l0 - m - lg, r1 = l1 - m - lg;
        if (flags[0]) {
            float* o = (float*)out + (size_t)row * NCLS + 2 * cl2;
            o[0] = r0; o[1] = r1;
        } else {
            uint32_t pk = (uint32_t)f2bf(r0) | ((uint32_t)f2bf(r1) << 16);
            *(uint32_t*)((u16*)out + (size_t)row * NCLS + 2 * cl2) = pk;
        }
    }
}

// ---------------- launch ----------------

extern "C" void kernel_launch(void* const* d_in, const int* in_sizes, int n_in,
                              void* d_out, int out_size, void* d_ws, size_t ws_size,
                              hipStream_t stream) {
    const void* x  = d_in[0];
    const int* ei  = (const int*)d_in[1];
    const void* W1 = d_in[2];
    const void* b1 = d_in[3];
    const void* W2 = d_in[4];
    const void* b2 = d_in[5];
    const void* W3 = d_in[6];
    const void* b3 = d_in[7];
    const void* W4 = d_in[8];
    const void* b4 = d_in[9];

    char* p = (char*)d_ws;
    auto alloc = [&](size_t b) -> char* {
        char* r = p;
        p += (b + 255) & ~(size_t)255;
        return r;
    };
    int*   flags = (int*)alloc(256);
    int*   cnt  = (int*)alloc((size_t)NN * 4);
    float* dinv = (float*)alloc((size_t)NN * 4);
    int*   rp   = (int*)alloc((size_t)(NN + 1) * 4);
    int*   col  = (int*)alloc((size_t)NE * 4);
    int*   bsum = (int*)alloc(4096);
    u16* xb  = (u16*)alloc((size_t)NN * FIN * 2);
    u16* W1t = (u16*)alloc((size_t)256 * 128 * 2);
    u16* W2t = (u16*)alloc((size_t)256 * 256 * 2);
    u16* W3t = (u16*)alloc((size_t)256 * 256 * 2);
    u16* W4t = (u16*)alloc((size_t)64 * 256 * 2);
    u16* bb1 = (u16*)alloc(512);
    u16* bb2 = (u16*)alloc(512);
    u16* bb3 = (u16*)alloc(512);
    u16* bb4 = (u16*)alloc(128);
    u16* bufA = (u16*)alloc((size_t)NN * HIDDEN * 2);
    u16* bufB = (u16*)alloc((size_t)NN * HIDDEN * 2);

    // CSR-build scratch aliased into bufB (used strictly before any conv)
    int* partial = (int*)bufB;                    // PRNG*SSL*RNG*4 = 12.8 MB

    k_detect<<<1, 256, 0, stream>>>((const u16*)x, ei, flags);

    // CSR build (atomic-free at device scope)
    k_histb<<<PRNG * SSL, 256, 0, stream>>>(ei, partial, flags);
    k_sumpart<<<(NN + 255) / 256, 256, 0, stream>>>(partial, cnt);
    k_scan1<<<(NN + 1023) / 1024, 256, 0, stream>>>(cnt, rp, bsum);
    k_scan2<<<1, 64, 0, stream>>>(bsum, (NN + 1023) / 1024);
    k_scan3o<<<(NN + 255) / 256, 256, 0, stream>>>(rp, bsum, cnt, dinv, partial);
    k_fillb<<<PRNG * SSL, 256, 0, stream>>>(ei, partial, col, flags);

    // weights / inputs to bf16
    k_cvt<<<(NN * FIN + 255) / 256, 256, 0, stream>>>(x, xb, NN * FIN, flags);
    k_cvt_bias<<<1, 256, 0, stream>>>(b1, b2, b3, b4, bb1, bb2, bb3, bb4, flags);
    k_transpose_all<<<704, 256, 0, stream>>>(W1, W2, W3, W4, W1t, W2t, W3t, W4t, flags);

    dim3 g128((NN + 127) / 128, 2);
    dim3 aggGrid((NN + 3) / 4);

    // conv1: x @ W1 (K=128)
    k_gemm128<<<g128, 256, 0, stream>>>(xb, W1t, dinv, bufB, 128);
    k_agg<<<aggGrid, 256, 0, stream>>>(bufB, rp, col, dinv, bb1, bufA);
    // conv2: @ W2
    k_gemm128<<<g128, 256, 0, stream>>>(bufA, W2t, dinv, bufB, 256);
    k_agg<<<aggGrid, 256, 0, stream>>>(bufB, rp, col, dinv, bb2, bufA);
    // conv3: @ W2 (reused)
    k_gemm128<<<g128, 256, 0, stream>>>(bufA, W2t, dinv, bufB, 256);
    k_agg<<<aggGrid, 256, 0, stream>>>(bufB, rp, col, dinv, bb2, bufA);
    // conv4: @ W3
    k_gemm128<<<g128, 256, 0, stream>>>(bufA, W3t, dinv, bufB, 256);
    k_agg<<<aggGrid, 256, 0, stream>>>(bufB, rp, col, dinv, bb3, bufA);
    // conv5: @ W4, padded to 64 cols, + fused log_softmax
    dim3 g64((NN + 63) / 64, 1);
    k_gemm64<<<g64, 256, 0, stream>>>(bufA, W4t, dinv, bufB, 256, 64);
    k_agg5<<<aggGrid, 256, 0, stream>>>(bufB, rp, col, dinv, bb4, d_out, flags);
}

// Round 8
// 967.947 us; speedup vs baseline: 1.2998x; 1.0266x over previous
//
#include <hip/hip_runtime.h>
#include <stdint.h>
#include <math.h>

#define NN   100000
#define FIN  128
#define HIDDEN 256
#define NCLS 40
#define NE   1600000

// CSR bucketing: P node-ranges x S edge-slices
#define PRNG 8
#define RNG  12500          // NN / PRNG
#define SSL  32
#define NES  50000          // NE / SSL

typedef unsigned short u16;
typedef __attribute__((ext_vector_type(8))) short s16x8;
typedef __attribute__((ext_vector_type(4))) float f32x4;

__device__ __forceinline__ float bf2f(unsigned short u) {
    union { float f; uint32_t i; } v; v.i = ((uint32_t)u) << 16; return v.f;
}
__device__ __forceinline__ unsigned short f2bf(float f) {
    union { float f; uint32_t i; } v; v.f = f;
    uint32_t r = v.i + 0x7fffu + ((v.i >> 16) & 1u);
    return (unsigned short)(r >> 16);
}

// ---------------- dtype detection ----------------
// flags[0] != 0 => float tensors are float32 (else bf16); flags[1] != 0 => edge_index int64
__global__ void k_detect(const u16* __restrict__ x16, const int* __restrict__ ei,
                         int* __restrict__ flags) {
    __shared__ int sh_nan, sh_odd;
    if (threadIdx.x == 0) { sh_nan = 0; sh_odd = 0; }
    __syncthreads();
    int t = threadIdx.x;
    int nan_cnt = 0;
    for (int i = t; i < 65536; i += 256) {
        u16 v = x16[i] & 0x7fff;
        if (v >= 0x7f80) nan_cnt++;
    }
    int odd_nz = 0;
    for (int i = t; i < 8192; i += 256) {
        if (ei[2 * i + 1] != 0) odd_nz++;
    }
    if (nan_cnt) atomicAdd(&sh_nan, nan_cnt);
    if (odd_nz) atomicAdd(&sh_odd, 1);
    __syncthreads();
    if (threadIdx.x == 0) {
        flags[0] = sh_nan;
        flags[1] = (sh_odd == 0) ? 1 : 0;
    }
}

// x -> bf16, prescaled by dinv[row]  (row = i / FIN)
__global__ void k_cvt_x(const void* __restrict__ src, const float* __restrict__ dinv,
                        u16* __restrict__ dst, const int* __restrict__ flags) {
    int i = blockIdx.x * 256 + threadIdx.x;
    if (i >= NN * FIN) return;
    float v = flags[0] ? ((const float*)src)[i] : bf2f(((const u16*)src)[i]);
    dst[i] = f2bf(v * dinv[i >> 7]);
}

// all four W [K,F] -> Wt [Fpad,K] bf16, plus bias conversion (block 704)
__global__ void k_transpose_all(const void* W1, const void* W2, const void* W3, const void* W4,
                                u16* W1t, u16* W2t, u16* W3t, u16* W4t,
                                const void* b1, const void* b2, const void* b3, const void* b4,
                                u16* o1, u16* o2, u16* o3, u16* o4,
                                const int* __restrict__ flags) {
    int b = blockIdx.x;
    int fl = flags[0];
    if (b == 704) {
        int t = threadIdx.x;
        o1[t] = fl ? f2bf(((const float*)b1)[t]) : ((const u16*)b1)[t];
        o2[t] = fl ? f2bf(((const float*)b2)[t]) : ((const u16*)b2)[t];
        o3[t] = fl ? f2bf(((const float*)b3)[t]) : ((const u16*)b3)[t];
        if (t < 64) o4[t] = (t < NCLS) ? (fl ? f2bf(((const float*)b4)[t]) : ((const u16*)b4)[t]) : (u16)0;
        return;
    }
    const void* W; u16* Wt; int K, F, Fpad, base;
    if (b < 128)      { W = W1; Wt = W1t; K = 128; F = 256; Fpad = 256; base = 0; }
    else if (b < 384) { W = W2; Wt = W2t; K = 256; F = 256; Fpad = 256; base = 128; }
    else if (b < 640) { W = W3; Wt = W3t; K = 256; F = 256; Fpad = 256; base = 384; }
    else              { W = W4; Wt = W4t; K = 256; F = 40;  Fpad = 64;  base = 640; }
    int idx = (b - base) * 256 + threadIdx.x;
    if (idx >= K * Fpad) return;
    int f = idx / K, k = idx - f * K;
    u16 v = 0;
    if (f < F) {
        if (fl) v = f2bf(((const float*)W)[(size_t)k * F + f]);
        else    v = ((const u16*)W)[(size_t)k * F + f];
    }
    Wt[idx] = v;
}

// ---------------- CSR build (no device atomics; reads edge_index directly) ----------------

__global__ __launch_bounds__(256) void k_histb(const int* __restrict__ ei,
                                               int* __restrict__ partial,
                                               const int* __restrict__ flags) {
    __shared__ int h[RNG];
    int p = blockIdx.x >> 5, s = blockIdx.x & 31;
    int t = threadIdx.x;
    int4 z4 = make_int4(0, 0, 0, 0);
    for (int i = t * 4; i < RNG; i += 1024) *(int4*)(h + i) = z4;
    __syncthreads();
    int base = s * NES;
    int lo = p * RNG;
    int nfull = NES & ~1023;
    if (flags[1]) {  // int64: dst at ei[2*(NE+e)], take even dwords
        const int* d = ei + 2 * (size_t)NE;
        for (int k = t * 4; k < nfull; k += 1024) {
            int4 q0 = *(const int4*)(d + 2 * (base + k));
            int4 q1 = *(const int4*)(d + 2 * (base + k) + 4);
            int a;
            a = q0.x - lo; if ((unsigned)a < RNG) atomicAdd(&h[a], 1);
            a = q0.z - lo; if ((unsigned)a < RNG) atomicAdd(&h[a], 1);
            a = q1.x - lo; if ((unsigned)a < RNG) atomicAdd(&h[a], 1);
            a = q1.z - lo; if ((unsigned)a < RNG) atomicAdd(&h[a], 1);
        }
        for (int k = nfull + t; k < NES; k += 256) {
            int a = d[2 * (base + k)] - lo;
            if ((unsigned)a < RNG) atomicAdd(&h[a], 1);
        }
    } else {
        const int* d = ei + NE;
        for (int k = t * 4; k < nfull; k += 1024) {
            int4 d4 = *(const int4*)(d + base + k);
            int a;
            a = d4.x - lo; if ((unsigned)a < RNG) atomicAdd(&h[a], 1);
            a = d4.y - lo; if ((unsigned)a < RNG) atomicAdd(&h[a], 1);
            a = d4.z - lo; if ((unsigned)a < RNG) atomicAdd(&h[a], 1);
            a = d4.w - lo; if ((unsigned)a < RNG) atomicAdd(&h[a], 1);
        }
        for (int k = nfull + t; k < NES; k += 256) {
            int a = d[base + k] - lo;
            if ((unsigned)a < RNG) atomicAdd(&h[a], 1);
        }
    }
    __syncthreads();
    int* out = partial + blockIdx.x * RNG;
    for (int i = t * 4; i < RNG; i += 1024) *(int4*)(out + i) = *(const int4*)(h + i);
}

// fused: per-node degree (sum of 32 partial slices) + block-local exclusive prefix
__global__ __launch_bounds__(256) void k_scan1(const int* __restrict__ partial,
                                               int* __restrict__ cnt,
                                               int* __restrict__ out,
                                               int* __restrict__ bsum) {
    __shared__ int sh[256];
    int t = threadIdx.x;
    int base = blockIdx.x * 1024 + t * 4;
    int v0 = 0, v1 = 0, v2 = 0, v3 = 0;
    if (base < NN) {   // NN%4==0 and base%4==0 => all 4 in-bounds
        int p = base / RNG, il = base - p * RNG;
        const int* q = partial + (p * SSL) * RNG + il;
        int4 acc = make_int4(0, 0, 0, 0);
#pragma unroll
        for (int s = 0; s < SSL; ++s) {
            int4 w = *(const int4*)(q + s * RNG);
            acc.x += w.x; acc.y += w.y; acc.z += w.z; acc.w += w.w;
        }
        v0 = acc.x; v1 = acc.y; v2 = acc.z; v3 = acc.w;
        *(int4*)(cnt + base) = acc;
    }
    int s = v0 + v1 + v2 + v3;
    sh[t] = s;
    __syncthreads();
    for (int off = 1; off < 256; off <<= 1) {
        int x = (t >= off) ? sh[t - off] : 0;
        __syncthreads();
        sh[t] += x;
        __syncthreads();
    }
    int ex = sh[t] - s;
    if (base < NN) {
        int4 o = make_int4(ex, ex + v0, ex + v0 + v1, ex + v0 + v1 + v2);
        *(int4*)(out + base) = o;
    }
    if (t == 255) bsum[blockIdx.x] = sh[255];
}

__global__ void k_scan2(int* bsum, int nb) {
    if (threadIdx.x == 0 && blockIdx.x == 0) {
        int run = 0;
        for (int i = 0; i < nb; ++i) { int t = bsum[i]; bsum[i] = run; run += t; }
    }
}

// finalize rp, dinv, and convert partial -> absolute slice offsets
__global__ void k_scan3o(int* __restrict__ rp, const int* __restrict__ bsum,
                         const int* __restrict__ cnt, float* __restrict__ dinv,
                         int* __restrict__ partial) {
    int i = blockIdx.x * 256 + threadIdx.x;
    if (i < NN) {
        int v = rp[i] + bsum[i >> 10];
        rp[i] = v;
        dinv[i] = rsqrtf((float)(cnt[i] + 1));
        int p = i / RNG, il = i - p * RNG;
        int* q = partial + (p * SSL) * RNG + il;
        int run = v;
#pragma unroll
        for (int s = 0; s < SSL; ++s) { int t = q[s * RNG]; q[s * RNG] = run; run += t; }
    }
    if (i == 0) rp[NN] = NE;
}

__global__ __launch_bounds__(256) void k_fillb(const int* __restrict__ ei,
                                               const int* __restrict__ offs,
                                               int* __restrict__ col,
                                               const int* __restrict__ flags) {
    __shared__ int h[RNG];
    int p = blockIdx.x >> 5, s = blockIdx.x & 31;
    int t = threadIdx.x;
    const int* o = offs + blockIdx.x * RNG;
    for (int i = t * 4; i < RNG; i += 1024) *(int4*)(h + i) = *(const int4*)(o + i);
    __syncthreads();
    int base = s * NES;
    int lo = p * RNG;
    int nfull = NES & ~1023;
    if (flags[1]) {
        const int* d = ei + 2 * (size_t)NE;
        const int* sp = ei;
        for (int k = t * 4; k < nfull; k += 1024) {
            int4 q0 = *(const int4*)(d + 2 * (base + k));
            int4 q1 = *(const int4*)(d + 2 * (base + k) + 4);
            int4 r0 = *(const int4*)(sp + 2 * (base + k));
            int4 r1 = *(const int4*)(sp + 2 * (base + k) + 4);
            int a;
            a = q0.x - lo; if ((unsigned)a < RNG) col[atomicAdd(&h[a], 1)] = r0.x;
            a = q0.z - lo; if ((unsigned)a < RNG) col[atomicAdd(&h[a], 1)] = r0.z;
            a = q1.x - lo; if ((unsigned)a < RNG) col[atomicAdd(&h[a], 1)] = r1.x;
            a = q1.z - lo; if ((unsigned)a < RNG) col[atomicAdd(&h[a], 1)] = r1.z;
        }
        for (int k = nfull + t; k < NES; k += 256) {
            int a = d[2 * (base + k)] - lo;
            if ((unsigned)a < RNG) col[atomicAdd(&h[a], 1)] = sp[2 * (base + k)];
        }
    } else {
        const int* d = ei + NE;
        const int* sp = ei;
        for (int k = t * 4; k < nfull; k += 1024) {
            int4 d4 = *(const int4*)(d + base + k);
            int4 s4 = *(const int4*)(sp + base + k);
            int a;
            a = d4.x - lo; if ((unsigned)a < RNG) col[atomicAdd(&h[a], 1)] = s4.x;
            a = d4.y - lo; if ((unsigned)a < RNG) col[atomicAdd(&h[a], 1)] = s4.y;
            a = d4.z - lo; if ((unsigned)a < RNG) col[atomicAdd(&h[a], 1)] = s4.z;
            a = d4.w - lo; if ((unsigned)a < RNG) col[atomicAdd(&h[a], 1)] = s4.w;
        }
        for (int k = nfull + t; k < NES; k += 256) {
            int a = d[base + k] - lo;
            if ((unsigned)a < RNG) col[atomicAdd(&h[a], 1)] = sp[base + k];
        }
    }
}

// ---------------- GEMM 128x128 (m97 structure): C = dinv[row]*(A@Wt^T) ----------------

#define GLL(g, l) __builtin_amdgcn_global_load_lds( \
    (const __attribute__((address_space(1))) unsigned int*)(g), \
    (__attribute__((address_space(3))) unsigned int*)(l), 16, 0, 0)

__global__ __launch_bounds__(256) void k_gemm128(const u16* __restrict__ A,
                                                 const u16* __restrict__ Wt,
                                                 const float* __restrict__ dinv,
                                                 u16* __restrict__ C,
                                                 int K) {
    __shared__ __align__(16) u16 As[128 * 32];
    __shared__ __align__(16) u16 Bs[128 * 32];
    int t = threadIdx.x;
    int bm = blockIdx.x, bn = blockIdx.y;
    int rowBase = bm * 128;
    int w = t >> 6, lane = t & 63;
    int wm = w >> 1, wn = w & 1;
    int lrow = lane & 15, lq = lane >> 4;

    f32x4 acc[4][4] = {};

    int r0 = t >> 2;
    int seg = (t & 3) * 8;
    int ar0 = rowBase + r0;       if (ar0 > NN - 1) ar0 = NN - 1;
    int ar1 = rowBase + 64 + r0;  if (ar1 > NN - 1) ar1 = NN - 1;
    const u16* a0p = A + (size_t)ar0 * K + seg;
    const u16* a1p = A + (size_t)ar1 * K + seg;
    const u16* b0p = Wt + (size_t)(bn * 128 + r0) * K + seg;
    const u16* b1p = Wt + (size_t)(bn * 128 + 64 + r0) * K + seg;
    u16* As0 = As + t * 8;
    u16* As1 = As + 2048 + t * 8;
    u16* Bs0 = Bs + t * 8;
    u16* Bs1 = Bs + 2048 + t * 8;

    int nK = K >> 5;
    for (int kt = 0; kt < nK; ++kt) {
        GLL(a0p, As0);
        GLL(a1p, As1);
        GLL(b0p, Bs0);
        GLL(b1p, Bs1);
        a0p += 32; a1p += 32; b0p += 32; b1p += 32;
        __syncthreads();
        s16x8 af[4], bf[4];
#pragma unroll
        for (int i = 0; i < 4; ++i)
            af[i] = *(const s16x8*)(As + (wm * 64 + i * 16 + lrow) * 32 + lq * 8);
#pragma unroll
        for (int j = 0; j < 4; ++j)
            bf[j] = *(const s16x8*)(Bs + (wn * 64 + j * 16 + lrow) * 32 + lq * 8);
#pragma unroll
        for (int i = 0; i < 4; ++i)
#pragma unroll
            for (int j = 0; j < 4; ++j)
                acc[i][j] = __builtin_amdgcn_mfma_f32_16x16x32_bf16(af[i], bf[j], acc[i][j], 0, 0, 0);
        __syncthreads();
    }

#pragma unroll
    for (int i = 0; i < 4; ++i) {
#pragma unroll
        for (int rr = 0; rr < 4; ++rr) {
            int row = rowBase + wm * 64 + i * 16 + lq * 4 + rr;
            if (row < NN) {
                float d = dinv[row];
#pragma unroll
                for (int j = 0; j < 4; ++j) {
                    int colg = bn * 128 + wn * 64 + j * 16 + lrow;
                    C[(size_t)row * HIDDEN + colg] = f2bf(acc[i][j][rr] * d);
                }
            }
        }
    }
}

// variant with fused epilogue: C = relu(dinv[row]*acc + bias[col])  (conv1 after pre-agg)
__global__ __launch_bounds__(256) void k_gemm128_br(const u16* __restrict__ A,
                                                    const u16* __restrict__ Wt,
                                                    const float* __restrict__ dinv,
                                                    const u16* __restrict__ bias,
                                                    u16* __restrict__ C,
                                                    int K) {
    __shared__ __align__(16) u16 As[128 * 32];
    __shared__ __align__(16) u16 Bs[128 * 32];
    int t = threadIdx.x;
    int bm = blockIdx.x, bn = blockIdx.y;
    int rowBase = bm * 128;
    int w = t >> 6, lane = t & 63;
    int wm = w >> 1, wn = w & 1;
    int lrow = lane & 15, lq = lane >> 4;

    f32x4 acc[4][4] = {};

    int r0 = t >> 2;
    int seg = (t & 3) * 8;
    int ar0 = rowBase + r0;       if (ar0 > NN - 1) ar0 = NN - 1;
    int ar1 = rowBase + 64 + r0;  if (ar1 > NN - 1) ar1 = NN - 1;
    const u16* a0p = A + (size_t)ar0 * K + seg;
    const u16* a1p = A + (size_t)ar1 * K + seg;
    const u16* b0p = Wt + (size_t)(bn * 128 + r0) * K + seg;
    const u16* b1p = Wt + (size_t)(bn * 128 + 64 + r0) * K + seg;
    u16* As0 = As + t * 8;
    u16* As1 = As + 2048 + t * 8;
    u16* Bs0 = Bs + t * 8;
    u16* Bs1 = Bs + 2048 + t * 8;

    int nK = K >> 5;
    for (int kt = 0; kt < nK; ++kt) {
        GLL(a0p, As0);
        GLL(a1p, As1);
        GLL(b0p, Bs0);
        GLL(b1p, Bs1);
        a0p += 32; a1p += 32; b0p += 32; b1p += 32;
        __syncthreads();
        s16x8 af[4], bf[4];
#pragma unroll
        for (int i = 0; i < 4; ++i)
            af[i] = *(const s16x8*)(As + (wm * 64 + i * 16 + lrow) * 32 + lq * 8);
#pragma unroll
        for (int j = 0; j < 4; ++j)
            bf[j] = *(const s16x8*)(Bs + (wn * 64 + j * 16 + lrow) * 32 + lq * 8);
#pragma unroll
        for (int i = 0; i < 4; ++i)
#pragma unroll
            for (int j = 0; j < 4; ++j)
                acc[i][j] = __builtin_amdgcn_mfma_f32_16x16x32_bf16(af[i], bf[j], acc[i][j], 0, 0, 0);
        __syncthreads();
    }

    float bcol[4];
#pragma unroll
    for (int j = 0; j < 4; ++j)
        bcol[j] = bf2f(bias[bn * 128 + wn * 64 + j * 16 + lrow]);

#pragma unroll
    for (int i = 0; i < 4; ++i) {
#pragma unroll
        for (int rr = 0; rr < 4; ++rr) {
            int row = rowBase + wm * 64 + i * 16 + lq * 4 + rr;
            if (row < NN) {
                float d = dinv[row];
#pragma unroll
                for (int j = 0; j < 4; ++j) {
                    int colg = bn * 128 + wn * 64 + j * 16 + lrow;
                    C[(size_t)row * HIDDEN + colg] = f2bf(fmaxf(fmaf(d, acc[i][j][rr], bcol[j]), 0.f));
                }
            }
        }
    }
}

// ---------------- GEMM 64x64 (conv5) ----------------
#define LDT 40

__global__ __launch_bounds__(256) void k_gemm64(const u16* __restrict__ A,
                                                const u16* __restrict__ Wt,
                                                const float* __restrict__ dinv,
                                                u16* __restrict__ C,
                                                int K, int Fstore) {
    __shared__ __align__(16) u16 As[64 * LDT];
    __shared__ __align__(16) u16 Bs[64 * LDT];
    int t = threadIdx.x;
    int bm = blockIdx.x, bn = blockIdx.y;
    int rowBase = bm * 64;
    int r = t >> 2;
    int cseg = (t & 3) * 8;
    int w = t >> 6;
    int wm = w >> 1, wn = w & 1;
    int lane = t & 63;
    int lrow = lane & 15;
    int lq = lane >> 4;
    f32x4 acc[2][2] = {};

    int nK = K >> 5;
    for (int kt = 0; kt < nK; ++kt) {
        int k0 = kt * 32;
        uint4 av = make_uint4(0, 0, 0, 0);
        int arow = rowBase + r;
        if (arow < NN) av = *(const uint4*)(A + (size_t)arow * K + k0 + cseg);
        *(uint4*)(As + r * LDT + cseg) = av;
        uint4 bv = *(const uint4*)(Wt + (size_t)(bn * 64 + r) * K + k0 + cseg);
        *(uint4*)(Bs + r * LDT + cseg) = bv;
        __syncthreads();

        s16x8 afr[2], bfr[2];
        afr[0] = *(const s16x8*)(As + (wm * 32 + lrow) * LDT + lq * 8);
        afr[1] = *(const s16x8*)(As + (wm * 32 + 16 + lrow) * LDT + lq * 8);
        bfr[0] = *(const s16x8*)(Bs + (wn * 32 + lrow) * LDT + lq * 8);
        bfr[1] = *(const s16x8*)(Bs + (wn * 32 + 16 + lrow) * LDT + lq * 8);
#pragma unroll
        for (int i = 0; i < 2; ++i)
#pragma unroll
            for (int j = 0; j < 2; ++j)
                acc[i][j] = __builtin_amdgcn_mfma_f32_16x16x32_bf16(afr[i], bfr[j], acc[i][j], 0, 0, 0);
        __syncthreads();
    }

#pragma unroll
    for (int ti = 0; ti < 2; ++ti)
#pragma unroll
        for (int tj = 0; tj < 2; ++tj)
#pragma unroll
            for (int rr = 0; rr < 4; ++rr) {
                int row = rowBase + wm * 32 + ti * 16 + lq * 4 + rr;
                int colg = bn * 64 + wn * 32 + tj * 16 + lrow;
                if (row < NN && colg < Fstore)
                    C[(size_t)row * Fstore + colg] = f2bf(acc[ti][tj][rr] * dinv[row]);
            }
}

// ---------------- aggregation F=256 (round-4 structure: best measured) ----------------

__device__ __forceinline__ void acc8(float* a, uint4 v) {
    a[0] += bf2f((u16)(v.x & 0xffff)); a[1] += bf2f((u16)(v.x >> 16));
    a[2] += bf2f((u16)(v.y & 0xffff)); a[3] += bf2f((u16)(v.y >> 16));
    a[4] += bf2f((u16)(v.z & 0xffff)); a[5] += bf2f((u16)(v.z >> 16));
    a[6] += bf2f((u16)(v.w & 0xffff)); a[7] += bf2f((u16)(v.w >> 16));
}

__global__ __launch_bounds__(256) void k_agg(const u16* __restrict__ hs,
                                             const int* __restrict__ rp,
                                             const int* __restrict__ col,
                                             const float* __restrict__ dinv,
                                             const u16* __restrict__ bias,
                                             u16* __restrict__ out) {
    int row = blockIdx.x * 4 + (threadIdx.x >> 6);
    if (row >= NN) return;
    int lane = threadIdx.x & 63;
    int half = lane >> 5;
    int fb = (lane & 31) * 8;
    float a[8] = {0.f, 0.f, 0.f, 0.f, 0.f, 0.f, 0.f, 0.f};
    if (half == 0) acc8(a, *(const uint4*)(hs + (size_t)row * HIDDEN + fb));
    int p = rp[row] + half, p1 = rp[row + 1];
    for (; p + 6 < p1; p += 8) {
        int s0 = col[p], s1 = col[p + 2], s2 = col[p + 4], s3 = col[p + 6];
        uint4 v0 = *(const uint4*)(hs + (size_t)s0 * HIDDEN + fb);
        uint4 v1 = *(const uint4*)(hs + (size_t)s1 * HIDDEN + fb);
        uint4 v2 = *(const uint4*)(hs + (size_t)s2 * HIDDEN + fb);
        uint4 v3 = *(const uint4*)(hs + (size_t)s3 * HIDDEN + fb);
        acc8(a, v0);
        acc8(a, v1);
        acc8(a, v2);
        acc8(a, v3);
    }
    for (; p < p1; p += 2) {
        int s = col[p];
        acc8(a, *(const uint4*)(hs + (size_t)s * HIDDEN + fb));
    }
#pragma unroll
    for (int i = 0; i < 8; ++i) a[i] += __shfl_xor(a[i], 32);
    if (half == 0) {
        float d = dinv[row];
        uint4 bv = *(const uint4*)(bias + fb);
        float r0 = fmaxf(fmaf(d, a[0], bf2f((u16)(bv.x & 0xffff))), 0.f);
        float r1 = fmaxf(fmaf(d, a[1], bf2f((u16)(bv.x >> 16))), 0.f);
        float r2 = fmaxf(fmaf(d, a[2], bf2f((u16)(bv.y & 0xffff))), 0.f);
        float r3 = fmaxf(fmaf(d, a[3], bf2f((u16)(bv.y >> 16))), 0.f);
        float r4 = fmaxf(fmaf(d, a[4], bf2f((u16)(bv.z & 0xffff))), 0.f);
        float r5 = fmaxf(fmaf(d, a[5], bf2f((u16)(bv.z >> 16))), 0.f);
        float r6 = fmaxf(fmaf(d, a[6], bf2f((u16)(bv.w & 0xffff))), 0.f);
        float r7 = fmaxf(fmaf(d, a[7], bf2f((u16)(bv.w >> 16))), 0.f);
        uint4 o;
        o.x = (uint32_t)f2bf(r0) | ((uint32_t)f2bf(r1) << 16);
        o.y = (uint32_t)f2bf(r2) | ((uint32_t)f2bf(r3) << 16);
        o.z = (uint32_t)f2bf(r4) | ((uint32_t)f2bf(r5) << 16);
        o.w = (uint32_t)f2bf(r6) | ((uint32_t)f2bf(r7) << 16);
        *(uint4*)(out + (size_t)row * HIDDEN + fb) = o;
    }
}

// ---------------- conv1 pre-aggregation on prescaled x (128 features, 256 B rows) ----------------
// y[dst] = sum_{src in N(dst) + self} xb[src];  xb already prescaled by dinv[src].
__global__ __launch_bounds__(256) void k_aggx(const u16* __restrict__ xb,
                                              const int* __restrict__ rp,
                                              const int* __restrict__ col,
                                              u16* __restrict__ out) {
    int row = blockIdx.x * 4 + (threadIdx.x >> 6);
    if (row >= NN) return;
    int lane = threadIdx.x & 63;
    int half = lane >> 5;
    int fb = (lane & 31) * 4;
    float a0 = 0.f, a1 = 0.f, a2 = 0.f, a3 = 0.f;
    if (half == 0) {
        uint2 v = *(const uint2*)(xb + (size_t)row * FIN + fb);
        a0 = bf2f((u16)(v.x & 0xffff)); a1 = bf2f((u16)(v.x >> 16));
        a2 = bf2f((u16)(v.y & 0xffff)); a3 = bf2f((u16)(v.y >> 16));
    }
    int p = rp[row] + half, p1 = rp[row + 1];
    for (; p + 6 < p1; p += 8) {
        int s0 = col[p], s1 = col[p + 2], s2 = col[p + 4], s3 = col[p + 6];
        uint2 v0 = *(const uint2*)(xb + (size_t)s0 * FIN + fb);
        uint2 v1 = *(const uint2*)(xb + (size_t)s1 * FIN + fb);
        uint2 v2 = *(const uint2*)(xb + (size_t)s2 * FIN + fb);
        uint2 v3 = *(const uint2*)(xb + (size_t)s3 * FIN + fb);
        a0 += bf2f((u16)(v0.x & 0xffff)) + bf2f((u16)(v1.x & 0xffff))
            + bf2f((u16)(v2.x & 0xffff)) + bf2f((u16)(v3.x & 0xffff));
        a1 += bf2f((u16)(v0.x >> 16)) + bf2f((u16)(v1.x >> 16))
            + bf2f((u16)(v2.x >> 16)) + bf2f((u16)(v3.x >> 16));
        a2 += bf2f((u16)(v0.y & 0xffff)) + bf2f((u16)(v1.y & 0xffff))
            + bf2f((u16)(v2.y & 0xffff)) + bf2f((u16)(v3.y & 0xffff));
        a3 += bf2f((u16)(v0.y >> 16)) + bf2f((u16)(v1.y >> 16))
            + bf2f((u16)(v2.y >> 16)) + bf2f((u16)(v3.y >> 16));
    }
    for (; p < p1; p += 2) {
        int s = col[p];
        uint2 v = *(const uint2*)(xb + (size_t)s * FIN + fb);
        a0 += bf2f((u16)(v.x & 0xffff)); a1 += bf2f((u16)(v.x >> 16));
        a2 += bf2f((u16)(v.y & 0xffff)); a3 += bf2f((u16)(v.y >> 16));
    }
    a0 += __shfl_xor(a0, 32); a1 += __shfl_xor(a1, 32);
    a2 += __shfl_xor(a2, 32); a3 += __shfl_xor(a3, 32);
    if (half == 0) {
        uint2 o;
        o.x = (uint32_t)f2bf(a0) | ((uint32_t)f2bf(a1) << 16);
        o.y = (uint32_t)f2bf(a2) | ((uint32_t)f2bf(a3) << 16);
        *(uint2*)(out + (size_t)row * FIN + fb) = o;
    }
}

// ---------------- last layer: hs padded to 64 cols; agg + bias + log_softmax ----------------
__global__ __launch_bounds__(256) void k_agg5(const u16* __restrict__ hs,
                                              const int* __restrict__ rp,
                                              const int* __restrict__ col,
                                              const float* __restrict__ dinv,
                                              const u16* __restrict__ bias,
                                              void* __restrict__ out,
                                              const int* __restrict__ flags) {
    int row = blockIdx.x * 4 + (threadIdx.x >> 6);
    if (row >= NN) return;
    int lane = threadIdx.x & 63;
    int half = lane >> 5;
    int cl2 = lane & 31;                 // class-pair index (2 classes per lane)
    float a0 = 0.f, a1 = 0.f;
    if (half == 0) {
        uint32_t v = *(const uint32_t*)(hs + (size_t)row * 64 + 2 * cl2);
        a0 = bf2f((u16)(v & 0xffff)); a1 = bf2f((u16)(v >> 16));
    }
    int p = rp[row] + half, p1 = rp[row + 1];
    for (; p + 6 < p1; p += 8) {
        int s0 = col[p], s1 = col[p + 2], s2 = col[p + 4], s3 = col[p + 6];
        uint32_t v0 = *(const uint32_t*)(hs + (size_t)s0 * 64 + 2 * cl2);
        uint32_t v1 = *(const uint32_t*)(hs + (size_t)s1 * 64 + 2 * cl2);
        uint32_t v2 = *(const uint32_t*)(hs + (size_t)s2 * 64 + 2 * cl2);
        uint32_t v3 = *(const uint32_t*)(hs + (size_t)s3 * 64 + 2 * cl2);
        a0 += bf2f((u16)(v0 & 0xffff)) + bf2f((u16)(v1 & 0xffff))
            + bf2f((u16)(v2 & 0xffff)) + bf2f((u16)(v3 & 0xffff));
        a1 += bf2f((u16)(v0 >> 16)) + bf2f((u16)(v1 >> 16))
            + bf2f((u16)(v2 >> 16)) + bf2f((u16)(v3 >> 16));
    }
    for (; p < p1; p += 2) {
        int s = col[p];
        uint32_t v = *(const uint32_t*)(hs + (size_t)s * 64 + 2 * cl2);
        a0 += bf2f((u16)(v & 0xffff));
        a1 += bf2f((u16)(v >> 16));
    }
    a0 += __shfl_xor(a0, 32);
    a1 += __shfl_xor(a1, 32);
    bool act = cl2 < (NCLS / 2);
    float d = dinv[row];
    uint32_t bv = *(const uint32_t*)(bias + 2 * cl2);
    float l0 = act ? fmaf(d, a0, bf2f((u16)(bv & 0xffff))) : -1e30f;
    float l1 = act ? fmaf(d, a1, bf2f((u16)(bv >> 16))) : -1e30f;
    float m = fmaxf(l0, l1);
#pragma unroll
    for (int off = 16; off > 0; off >>= 1) m = fmaxf(m, __shfl_xor(m, off));
    float e = act ? (__expf(l0 - m) + __expf(l1 - m)) : 0.f;
    float ss = e;
#pragma unroll
    for (int off = 16; off > 0; off >>= 1) ss += __shfl_xor(ss, off);
    if (act && half == 0) {
        float lg = __logf(ss);
        float r0 = l0 - m - lg, r1 = l1 - m - lg;
        if (flags[0]) {
            float* o = (float*)out + (size_t)row * NCLS + 2 * cl2;
            o[0] = r0; o[1] = r1;
        } else {
            uint32_t pk = (uint32_t)f2bf(r0) | ((uint32_t)f2bf(r1) << 16);
            *(uint32_t*)((u16*)out + (size_t)row * NCLS + 2 * cl2) = pk;
        }
    }
}

// ---------------- launch ----------------

extern "C" void kernel_launch(void* const* d_in, const int* in_sizes, int n_in,
                              void* d_out, int out_size, void* d_ws, size_t ws_size,
                              hipStream_t stream) {
    const void* x  = d_in[0];
    const int* ei  = (const int*)d_in[1];
    const void* W1 = d_in[2];
    const void* b1 = d_in[3];
    const void* W2 = d_in[4];
    const void* b2 = d_in[5];
    const void* W3 = d_in[6];
    const void* b3 = d_in[7];
    const void* W4 = d_in[8];
    const void* b4 = d_in[9];

    char* p = (char*)d_ws;
    auto alloc = [&](size_t b) -> char* {
        char* r = p;
        p += (b + 255) & ~(size_t)255;
        return r;
    };
    int*   flags = (int*)alloc(256);
    int*   cnt  = (int*)alloc((size_t)NN * 4);
    float* dinv = (float*)alloc((size_t)NN * 4);
    int*   rp   = (int*)alloc((size_t)(NN + 1) * 4);
    int*   col  = (int*)alloc((size_t)NE * 4);
    int*   bsum = (int*)alloc(4096);
    u16* xb  = (u16*)alloc((size_t)NN * FIN * 2);
    u16* W1t = (u16*)alloc((size_t)256 * 128 * 2);
    u16* W2t = (u16*)alloc((size_t)256 * 256 * 2);
    u16* W3t = (u16*)alloc((size_t)256 * 256 * 2);
    u16* W4t = (u16*)alloc((size_t)64 * 256 * 2);
    u16* bb1 = (u16*)alloc(512);
    u16* bb2 = (u16*)alloc(512);
    u16* bb3 = (u16*)alloc(512);
    u16* bb4 = (u16*)alloc(128);
    u16* bufA = (u16*)alloc((size_t)NN * HIDDEN * 2);
    u16* bufB = (u16*)alloc((size_t)NN * HIDDEN * 2);

    // CSR-build scratch aliased into bufB (used strictly before any conv)
    int* partial = (int*)bufB;                    // PRNG*SSL*RNG*4 = 12.8 MB

    k_detect<<<1, 256, 0, stream>>>((const u16*)x, ei, flags);

    // CSR build (atomic-free at device scope)
    k_histb<<<PRNG * SSL, 256, 0, stream>>>(ei, partial, flags);
    k_scan1<<<(NN + 1023) / 1024, 256, 0, stream>>>(partial, cnt, rp, bsum);
    k_scan2<<<1, 64, 0, stream>>>(bsum, (NN + 1023) / 1024);
    k_scan3o<<<(NN + 255) / 256, 256, 0, stream>>>(rp, bsum, cnt, dinv, partial);
    k_fillb<<<PRNG * SSL, 256, 0, stream>>>(ei, partial, col, flags);

    // inputs/weights to bf16 (x prescaled by dinv)
    k_cvt_x<<<(NN * FIN + 255) / 256, 256, 0, stream>>>(x, dinv, xb, flags);
    k_transpose_all<<<705, 256, 0, stream>>>(W1, W2, W3, W4, W1t, W2t, W3t, W4t,
                                             b1, b2, b3, b4, bb1, bb2, bb3, bb4, flags);

    dim3 g128((NN + 127) / 128, 2);
    dim3 aggGrid((NN + 3) / 4);

    // conv1 (aggregate-then-transform): y = A_hat_scaled @ xb; h1 = relu(dinv*(y W1) + b1)
    k_aggx<<<aggGrid, 256, 0, stream>>>(xb, rp, col, bufB);
    k_gemm128_br<<<g128, 256, 0, stream>>>(bufB, W1t, dinv, bb1, bufA, 128);
    // conv2: @ W2
    k_gemm128<<<g128, 256, 0, stream>>>(bufA, W2t, dinv, bufB, 256);
    k_agg<<<aggGrid, 256, 0, stream>>>(bufB, rp, col, dinv, bb2, bufA);
    // conv3: @ W2 (reused)
    k_gemm128<<<g128, 256, 0, stream>>>(bufA, W2t, dinv, bufB, 256);
    k_agg<<<aggGrid, 256, 0, stream>>>(bufB, rp, col, dinv, bb2, bufA);
    // conv4: @ W3
    k_gemm128<<<g128, 256, 0, stream>>>(bufA, W3t, dinv, bufB, 256);
    k_agg<<<aggGrid, 256, 0, stream>>>(bufB, rp, col, dinv, bb3, bufA);
    // conv5: @ W4, padded to 64 cols, + fused log_softmax
    dim3 g64((NN + 63) / 64, 1);
    k_gemm64<<<g64, 256, 0, stream>>>(bufA, W4t, dinv, bufB, 256, 64);
    k_agg5<<<aggGrid, 256, 0, stream>>>(bufB, rp, col, dinv, bb4, d_out, flags);
}

// Round 9
// 965.772 us; speedup vs baseline: 1.3027x; 1.0023x over previous
//
#include <hip/hip_runtime.h>
#include <stdint.h>
#include <math.h>

#define NN   100000
#define FIN  128
#define HIDDEN 256
#define NCLS 40
#define NE   1600000

// CSR bucketing: P node-ranges x S edge-slices
#define PRNG 8
#define RNG  12500          // NN / PRNG
#define SSL  32
#define NES  50000          // NE / SSL

typedef unsigned short u16;
typedef __attribute__((ext_vector_type(8))) short s16x8;
typedef __attribute__((ext_vector_type(4))) float f32x4;

__device__ __forceinline__ float bf2f(unsigned short u) {
    union { float f; uint32_t i; } v; v.i = ((uint32_t)u) << 16; return v.f;
}
__device__ __forceinline__ unsigned short f2bf(float f) {
    union { float f; uint32_t i; } v; v.f = f;
    uint32_t r = v.i + 0x7fffu + ((v.i >> 16) & 1u);
    return (unsigned short)(r >> 16);
}

// ---------------- dtype detection ----------------
__global__ void k_detect(const u16* __restrict__ x16, const int* __restrict__ ei,
                         int* __restrict__ flags) {
    __shared__ int sh_nan, sh_odd;
    if (threadIdx.x == 0) { sh_nan = 0; sh_odd = 0; }
    __syncthreads();
    int t = threadIdx.x;
    int nan_cnt = 0;
    for (int i = t; i < 65536; i += 256) {
        u16 v = x16[i] & 0x7fff;
        if (v >= 0x7f80) nan_cnt++;
    }
    int odd_nz = 0;
    for (int i = t; i < 8192; i += 256) {
        if (ei[2 * i + 1] != 0) odd_nz++;
    }
    if (nan_cnt) atomicAdd(&sh_nan, nan_cnt);
    if (odd_nz) atomicAdd(&sh_odd, 1);
    __syncthreads();
    if (threadIdx.x == 0) {
        flags[0] = sh_nan;
        flags[1] = (sh_odd == 0) ? 1 : 0;
    }
}

// x -> bf16, prescaled by dinv[row]  (row = i / FIN)
__global__ void k_cvt_x(const void* __restrict__ src, const float* __restrict__ dinv,
                        u16* __restrict__ dst, const int* __restrict__ flags) {
    int i = blockIdx.x * 256 + threadIdx.x;
    if (i >= NN * FIN) return;
    float v = flags[0] ? ((const float*)src)[i] : bf2f(((const u16*)src)[i]);
    dst[i] = f2bf(v * dinv[i >> 7]);
}

// all four W [K,F] -> Wt [Fpad,K] bf16, plus bias conversion (block 704)
__global__ void k_transpose_all(const void* W1, const void* W2, const void* W3, const void* W4,
                                u16* W1t, u16* W2t, u16* W3t, u16* W4t,
                                const void* b1, const void* b2, const void* b3, const void* b4,
                                u16* o1, u16* o2, u16* o3, u16* o4,
                                const int* __restrict__ flags) {
    int b = blockIdx.x;
    int fl = flags[0];
    if (b == 704) {
        int t = threadIdx.x;
        o1[t] = fl ? f2bf(((const float*)b1)[t]) : ((const u16*)b1)[t];
        o2[t] = fl ? f2bf(((const float*)b2)[t]) : ((const u16*)b2)[t];
        o3[t] = fl ? f2bf(((const float*)b3)[t]) : ((const u16*)b3)[t];
        if (t < 64) o4[t] = (t < NCLS) ? (fl ? f2bf(((const float*)b4)[t]) : ((const u16*)b4)[t]) : (u16)0;
        return;
    }
    const void* W; u16* Wt; int K, F, Fpad, base;
    if (b < 128)      { W = W1; Wt = W1t; K = 128; F = 256; Fpad = 256; base = 0; }
    else if (b < 384) { W = W2; Wt = W2t; K = 256; F = 256; Fpad = 256; base = 128; }
    else if (b < 640) { W = W3; Wt = W3t; K = 256; F = 256; Fpad = 256; base = 384; }
    else              { W = W4; Wt = W4t; K = 256; F = 40;  Fpad = 64;  base = 640; }
    int idx = (b - base) * 256 + threadIdx.x;
    if (idx >= K * Fpad) return;
    int f = idx / K, k = idx - f * K;
    u16 v = 0;
    if (f < F) {
        if (fl) v = f2bf(((const float*)W)[(size_t)k * F + f]);
        else    v = ((const u16*)W)[(size_t)k * F + f];
    }
    Wt[idx] = v;
}

// ---------------- CSR build (no device atomics; reads edge_index directly) ----------------

__global__ __launch_bounds__(256) void k_histb(const int* __restrict__ ei,
                                               int* __restrict__ partial,
                                               const int* __restrict__ flags) {
    __shared__ int h[RNG];
    int p = blockIdx.x >> 5, s = blockIdx.x & 31;
    int t = threadIdx.x;
    int4 z4 = make_int4(0, 0, 0, 0);
    for (int i = t * 4; i < RNG; i += 1024) *(int4*)(h + i) = z4;
    __syncthreads();
    int base = s * NES;
    int lo = p * RNG;
    int nfull = NES & ~1023;
    if (flags[1]) {  // int64: dst at ei[2*(NE+e)], take even dwords
        const int* d = ei + 2 * (size_t)NE;
        for (int k = t * 4; k < nfull; k += 1024) {
            int4 q0 = *(const int4*)(d + 2 * (base + k));
            int4 q1 = *(const int4*)(d + 2 * (base + k) + 4);
            int a;
            a = q0.x - lo; if ((unsigned)a < RNG) atomicAdd(&h[a], 1);
            a = q0.z - lo; if ((unsigned)a < RNG) atomicAdd(&h[a], 1);
            a = q1.x - lo; if ((unsigned)a < RNG) atomicAdd(&h[a], 1);
            a = q1.z - lo; if ((unsigned)a < RNG) atomicAdd(&h[a], 1);
        }
        for (int k = nfull + t; k < NES; k += 256) {
            int a = d[2 * (base + k)] - lo;
            if ((unsigned)a < RNG) atomicAdd(&h[a], 1);
        }
    } else {
        const int* d = ei + NE;
        for (int k = t * 4; k < nfull; k += 1024) {
            int4 d4 = *(const int4*)(d + base + k);
            int a;
            a = d4.x - lo; if ((unsigned)a < RNG) atomicAdd(&h[a], 1);
            a = d4.y - lo; if ((unsigned)a < RNG) atomicAdd(&h[a], 1);
            a = d4.z - lo; if ((unsigned)a < RNG) atomicAdd(&h[a], 1);
            a = d4.w - lo; if ((unsigned)a < RNG) atomicAdd(&h[a], 1);
        }
        for (int k = nfull + t; k < NES; k += 256) {
            int a = d[base + k] - lo;
            if ((unsigned)a < RNG) atomicAdd(&h[a], 1);
        }
    }
    __syncthreads();
    int* out = partial + blockIdx.x * RNG;
    for (int i = t * 4; i < RNG; i += 1024) *(int4*)(out + i) = *(const int4*)(h + i);
}

// fused: per-node degree (sum of 32 partial slices) + block-local exclusive prefix
__global__ __launch_bounds__(256) void k_scan1(const int* __restrict__ partial,
                                               int* __restrict__ cnt,
                                               int* __restrict__ out,
                                               int* __restrict__ bsum) {
    __shared__ int sh[256];
    int t = threadIdx.x;
    int base = blockIdx.x * 1024 + t * 4;
    int v0 = 0, v1 = 0, v2 = 0, v3 = 0;
    if (base < NN) {
        int p = base / RNG, il = base - p * RNG;
        const int* q = partial + (p * SSL) * RNG + il;
        int4 acc = make_int4(0, 0, 0, 0);
#pragma unroll
        for (int s = 0; s < SSL; ++s) {
            int4 w = *(const int4*)(q + s * RNG);
            acc.x += w.x; acc.y += w.y; acc.z += w.z; acc.w += w.w;
        }
        v0 = acc.x; v1 = acc.y; v2 = acc.z; v3 = acc.w;
        *(int4*)(cnt + base) = acc;
    }
    int s = v0 + v1 + v2 + v3;
    sh[t] = s;
    __syncthreads();
    for (int off = 1; off < 256; off <<= 1) {
        int x = (t >= off) ? sh[t - off] : 0;
        __syncthreads();
        sh[t] += x;
        __syncthreads();
    }
    int ex = sh[t] - s;
    if (base < NN) {
        int4 o = make_int4(ex, ex + v0, ex + v0 + v1, ex + v0 + v1 + v2);
        *(int4*)(out + base) = o;
    }
    if (t == 255) bsum[blockIdx.x] = sh[255];
}

__global__ void k_scan2(int* bsum, int nb) {
    if (threadIdx.x == 0 && blockIdx.x == 0) {
        int run = 0;
        for (int i = 0; i < nb; ++i) { int t = bsum[i]; bsum[i] = run; run += t; }
    }
}

// finalize rp, dinv, and convert partial -> absolute slice offsets
__global__ void k_scan3o(int* __restrict__ rp, const int* __restrict__ bsum,
                         const int* __restrict__ cnt, float* __restrict__ dinv,
                         int* __restrict__ partial) {
    int i = blockIdx.x * 256 + threadIdx.x;
    if (i < NN) {
        int v = rp[i] + bsum[i >> 10];
        rp[i] = v;
        dinv[i] = rsqrtf((float)(cnt[i] + 1));
        int p = i / RNG, il = i - p * RNG;
        int* q = partial + (p * SSL) * RNG + il;
        int run = v;
#pragma unroll
        for (int s = 0; s < SSL; ++s) { int t = q[s * RNG]; q[s * RNG] = run; run += t; }
    }
    if (i == 0) rp[NN] = NE;
}

__global__ __launch_bounds__(256) void k_fillb(const int* __restrict__ ei,
                                               const int* __restrict__ offs,
                                               int* __restrict__ col,
                                               const int* __restrict__ flags) {
    __shared__ int h[RNG];
    int p = blockIdx.x >> 5, s = blockIdx.x & 31;
    int t = threadIdx.x;
    const int* o = offs + blockIdx.x * RNG;
    for (int i = t * 4; i < RNG; i += 1024) *(int4*)(h + i) = *(const int4*)(o + i);
    __syncthreads();
    int base = s * NES;
    int lo = p * RNG;
    int nfull = NES & ~1023;
    if (flags[1]) {
        const int* d = ei + 2 * (size_t)NE;
        const int* sp = ei;
        for (int k = t * 4; k < nfull; k += 1024) {
            int4 q0 = *(const int4*)(d + 2 * (base + k));
            int4 q1 = *(const int4*)(d + 2 * (base + k) + 4);
            int4 r0 = *(const int4*)(sp + 2 * (base + k));
            int4 r1 = *(const int4*)(sp + 2 * (base + k) + 4);
            int a;
            a = q0.x - lo; if ((unsigned)a < RNG) col[atomicAdd(&h[a], 1)] = r0.x;
            a = q0.z - lo; if ((unsigned)a < RNG) col[atomicAdd(&h[a], 1)] = r0.z;
            a = q1.x - lo; if ((unsigned)a < RNG) col[atomicAdd(&h[a], 1)] = r1.x;
            a = q1.z - lo; if ((unsigned)a < RNG) col[atomicAdd(&h[a], 1)] = r1.z;
        }
        for (int k = nfull + t; k < NES; k += 256) {
            int a = d[2 * (base + k)] - lo;
            if ((unsigned)a < RNG) col[atomicAdd(&h[a], 1)] = sp[2 * (base + k)];
        }
    } else {
        const int* d = ei + NE;
        const int* sp = ei;
        for (int k = t * 4; k < nfull; k += 1024) {
            int4 d4 = *(const int4*)(d + base + k);
            int4 s4 = *(const int4*)(sp + base + k);
            int a;
            a = d4.x - lo; if ((unsigned)a < RNG) col[atomicAdd(&h[a], 1)] = s4.x;
            a = d4.y - lo; if ((unsigned)a < RNG) col[atomicAdd(&h[a], 1)] = s4.y;
            a = d4.z - lo; if ((unsigned)a < RNG) col[atomicAdd(&h[a], 1)] = s4.z;
            a = d4.w - lo; if ((unsigned)a < RNG) col[atomicAdd(&h[a], 1)] = s4.w;
        }
        for (int k = nfull + t; k < NES; k += 256) {
            int a = d[base + k] - lo;
            if ((unsigned)a < RNG) col[atomicAdd(&h[a], 1)] = sp[base + k];
        }
    }
}

// ---------------- Persistent-B GEMM: C[row, bn*128+c] = epi(A[NN,K] @ Wt^T) ----------------
// B half (128 cols x K) resident in LDS, blocked [K/32][128][32]; A double-buffered.
// grid (256, 2); grid-stride over row tiles. bias!=null => relu(dinv*acc+bias) else dinv*acc.

#define GLL(g, l) __builtin_amdgcn_global_load_lds( \
    (const __attribute__((address_space(1))) unsigned int*)(g), \
    (__attribute__((address_space(3))) unsigned int*)(l), 16, 0, 0)

#define NT128 ((NN + 127) / 128)

__global__ __launch_bounds__(256) void k_gemmP(const u16* __restrict__ A,
                                               const u16* __restrict__ Wt,
                                               const float* __restrict__ dinv,
                                               const u16* __restrict__ bias,
                                               u16* __restrict__ C,
                                               int K) {
    __shared__ __align__(16) u16 Bs[128 * 256];   // up to K=256, blocked [K/32][128][32]
    __shared__ __align__(16) u16 As[2 * 128 * 32];
    int t = threadIdx.x;
    int bn = blockIdx.y;
    int w = t >> 6, lane = t & 63;
    int wm = w >> 1, wn = w & 1;
    int lrow = lane & 15, lq = lane >> 4;
    int r0 = t >> 2;
    int seg = (t & 3) * 8;

    // ---- load B half once: rounds of 4 KB (64 lanes x 16 B x 4 waves) ----
    int rounds = K >> 4;                 // (128*K*2)/4096
    for (int r = 0; r < rounds; ++r) {
        int d = r * 4096 + t * 16;       // byte offset in blocked Bs
        int kt = d >> 13;                // 8192 B per [128][32] block
        int win = d & 8191;
        int row = win >> 6;              // 64 B per row
        int sg = (win & 63) >> 1;        // elem offset in row
        GLL(Wt + (size_t)(bn * 128 + row) * K + kt * 32 + sg, Bs + (d >> 1));
    }

    int nK = K >> 5;
    bool fuse = (bias != nullptr);
    float bcol[4];
#pragma unroll
    for (int j = 0; j < 4; ++j)
        bcol[j] = fuse ? bf2f(bias[bn * 128 + wn * 64 + j * 16 + lrow]) : 0.f;

    for (int tm = blockIdx.x; tm < NT128; tm += gridDim.x) {
        int rowBase = tm * 128;
        int ar0 = rowBase + r0;       if (ar0 > NN - 1) ar0 = NN - 1;
        int ar1 = rowBase + 64 + r0;  if (ar1 > NN - 1) ar1 = NN - 1;
        const u16* a0p = A + (size_t)ar0 * K + seg;
        const u16* a1p = A + (size_t)ar1 * K + seg;
        // prefetch kt=0 into buf 0
        GLL(a0p, As + t * 8);
        GLL(a1p, As + 2048 + t * 8);

        f32x4 acc[4][4] = {};
        int cur = 0;
        for (int kt = 0; kt < nK; ++kt) {
            __syncthreads();   // As[cur] ready; prev reads of other buf complete
            if (kt + 1 < nK) {
                int nxt = cur ^ 1;
                GLL(a0p + (kt + 1) * 32, As + nxt * 4096 + t * 8);
                GLL(a1p + (kt + 1) * 32, As + nxt * 4096 + 2048 + t * 8);
            }
            const u16* ab = As + cur * 4096;
            const u16* bb = Bs + kt * 4096;
            s16x8 af[4], bf[4];
#pragma unroll
            for (int i = 0; i < 4; ++i)
                af[i] = *(const s16x8*)(ab + (wm * 64 + i * 16 + lrow) * 32 + lq * 8);
#pragma unroll
            for (int j = 0; j < 4; ++j)
                bf[j] = *(const s16x8*)(bb + (wn * 64 + j * 16 + lrow) * 32 + lq * 8);
#pragma unroll
            for (int i = 0; i < 4; ++i)
#pragma unroll
                for (int j = 0; j < 4; ++j)
                    acc[i][j] = __builtin_amdgcn_mfma_f32_16x16x32_bf16(af[i], bf[j], acc[i][j], 0, 0, 0);
            cur ^= 1;
        }

#pragma unroll
        for (int i = 0; i < 4; ++i) {
#pragma unroll
            for (int rr = 0; rr < 4; ++rr) {
                int row = rowBase + wm * 64 + i * 16 + lq * 4 + rr;
                if (row < NN) {
                    float d = dinv[row];
#pragma unroll
                    for (int j = 0; j < 4; ++j) {
                        int colg = bn * 128 + wn * 64 + j * 16 + lrow;
                        float v = fuse ? fmaxf(fmaf(d, acc[i][j][rr], bcol[j]), 0.f)
                                       : acc[i][j][rr] * d;
                        C[(size_t)row * HIDDEN + colg] = f2bf(v);
                    }
                }
            }
        }
        __syncthreads();   // all waves done reading As before next tile's prefetch
    }
}

// ---------------- GEMM 64x64 (conv5) ----------------
#define LDT 40

__global__ __launch_bounds__(256) void k_gemm64(const u16* __restrict__ A,
                                                const u16* __restrict__ Wt,
                                                const float* __restrict__ dinv,
                                                u16* __restrict__ C,
                                                int K, int Fstore) {
    __shared__ __align__(16) u16 As[64 * LDT];
    __shared__ __align__(16) u16 Bs[64 * LDT];
    int t = threadIdx.x;
    int bm = blockIdx.x, bn = blockIdx.y;
    int rowBase = bm * 64;
    int r = t >> 2;
    int cseg = (t & 3) * 8;
    int w = t >> 6;
    int wm = w >> 1, wn = w & 1;
    int lane = t & 63;
    int lrow = lane & 15;
    int lq = lane >> 4;
    f32x4 acc[2][2] = {};

    int nK = K >> 5;
    for (int kt = 0; kt < nK; ++kt) {
        int k0 = kt * 32;
        uint4 av = make_uint4(0, 0, 0, 0);
        int arow = rowBase + r;
        if (arow < NN) av = *(const uint4*)(A + (size_t)arow * K + k0 + cseg);
        *(uint4*)(As + r * LDT + cseg) = av;
        uint4 bv = *(const uint4*)(Wt + (size_t)(bn * 64 + r) * K + k0 + cseg);
        *(uint4*)(Bs + r * LDT + cseg) = bv;
        __syncthreads();

        s16x8 afr[2], bfr[2];
        afr[0] = *(const s16x8*)(As + (wm * 32 + lrow) * LDT + lq * 8);
        afr[1] = *(const s16x8*)(As + (wm * 32 + 16 + lrow) * LDT + lq * 8);
        bfr[0] = *(const s16x8*)(Bs + (wn * 32 + lrow) * LDT + lq * 8);
        bfr[1] = *(const s16x8*)(Bs + (wn * 32 + 16 + lrow) * LDT + lq * 8);
#pragma unroll
        for (int i = 0; i < 2; ++i)
#pragma unroll
            for (int j = 0; j < 2; ++j)
                acc[i][j] = __builtin_amdgcn_mfma_f32_16x16x32_bf16(afr[i], bfr[j], acc[i][j], 0, 0, 0);
        __syncthreads();
    }

#pragma unroll
    for (int ti = 0; ti < 2; ++ti)
#pragma unroll
        for (int tj = 0; tj < 2; ++tj)
#pragma unroll
            for (int rr = 0; rr < 4; ++rr) {
                int row = rowBase + wm * 32 + ti * 16 + lq * 4 + rr;
                int colg = bn * 64 + wn * 32 + tj * 16 + lrow;
                if (row < NN && colg < Fstore)
                    C[(size_t)row * Fstore + colg] = f2bf(acc[ti][tj][rr] * dinv[row]);
            }
}

// ---------------- aggregation F=256 (round-4 structure: best measured) ----------------

__device__ __forceinline__ void acc8(float* a, uint4 v) {
    a[0] += bf2f((u16)(v.x & 0xffff)); a[1] += bf2f((u16)(v.x >> 16));
    a[2] += bf2f((u16)(v.y & 0xffff)); a[3] += bf2f((u16)(v.y >> 16));
    a[4] += bf2f((u16)(v.z & 0xffff)); a[5] += bf2f((u16)(v.z >> 16));
    a[6] += bf2f((u16)(v.w & 0xffff)); a[7] += bf2f((u16)(v.w >> 16));
}

__global__ __launch_bounds__(256) void k_agg(const u16* __restrict__ hs,
                                             const int* __restrict__ rp,
                                             const int* __restrict__ col,
                                             const float* __restrict__ dinv,
                                             const u16* __restrict__ bias,
                                             u16* __restrict__ out) {
    int row = blockIdx.x * 4 + (threadIdx.x >> 6);
    if (row >= NN) return;
    int lane = threadIdx.x & 63;
    int half = lane >> 5;
    int fb = (lane & 31) * 8;
    float a[8] = {0.f, 0.f, 0.f, 0.f, 0.f, 0.f, 0.f, 0.f};
    if (half == 0) acc8(a, *(const uint4*)(hs + (size_t)row * HIDDEN + fb));
    int p = rp[row] + half, p1 = rp[row + 1];
    for (; p + 6 < p1; p += 8) {
        int s0 = col[p], s1 = col[p + 2], s2 = col[p + 4], s3 = col[p + 6];
        uint4 v0 = *(const uint4*)(hs + (size_t)s0 * HIDDEN + fb);
        uint4 v1 = *(const uint4*)(hs + (size_t)s1 * HIDDEN + fb);
        uint4 v2 = *(const uint4*)(hs + (size_t)s2 * HIDDEN + fb);
        uint4 v3 = *(const uint4*)(hs + (size_t)s3 * HIDDEN + fb);
        acc8(a, v0);
        acc8(a, v1);
        acc8(a, v2);
        acc8(a, v3);
    }
    for (; p < p1; p += 2) {
        int s = col[p];
        acc8(a, *(const uint4*)(hs + (size_t)s * HIDDEN + fb));
    }
#pragma unroll
    for (int i = 0; i < 8; ++i) a[i] += __shfl_xor(a[i], 32);
    if (half == 0) {
        float d = dinv[row];
        uint4 bv = *(const uint4*)(bias + fb);
        float r0 = fmaxf(fmaf(d, a[0], bf2f((u16)(bv.x & 0xffff))), 0.f);
        float r1 = fmaxf(fmaf(d, a[1], bf2f((u16)(bv.x >> 16))), 0.f);
        float r2 = fmaxf(fmaf(d, a[2], bf2f((u16)(bv.y & 0xffff))), 0.f);
        float r3 = fmaxf(fmaf(d, a[3], bf2f((u16)(bv.y >> 16))), 0.f);
        float r4 = fmaxf(fmaf(d, a[4], bf2f((u16)(bv.z & 0xffff))), 0.f);
        float r5 = fmaxf(fmaf(d, a[5], bf2f((u16)(bv.z >> 16))), 0.f);
        float r6 = fmaxf(fmaf(d, a[6], bf2f((u16)(bv.w & 0xffff))), 0.f);
        float r7 = fmaxf(fmaf(d, a[7], bf2f((u16)(bv.w >> 16))), 0.f);
        uint4 o;
        o.x = (uint32_t)f2bf(r0) | ((uint32_t)f2bf(r1) << 16);
        o.y = (uint32_t)f2bf(r2) | ((uint32_t)f2bf(r3) << 16);
        o.z = (uint32_t)f2bf(r4) | ((uint32_t)f2bf(r5) << 16);
        o.w = (uint32_t)f2bf(r6) | ((uint32_t)f2bf(r7) << 16);
        *(uint4*)(out + (size_t)row * HIDDEN + fb) = o;
    }
}

// ---------------- conv1 pre-aggregation on prescaled x (128 features) ----------------
__global__ __launch_bounds__(256) void k_aggx(const u16* __restrict__ xb,
                                              const int* __restrict__ rp,
                                              const int* __restrict__ col,
                                              u16* __restrict__ out) {
    int row = blockIdx.x * 4 + (threadIdx.x >> 6);
    if (row >= NN) return;
    int lane = threadIdx.x & 63;
    int half = lane >> 5;
    int fb = (lane & 31) * 4;
    float a0 = 0.f, a1 = 0.f, a2 = 0.f, a3 = 0.f;
    if (half == 0) {
        uint2 v = *(const uint2*)(xb + (size_t)row * FIN + fb);
        a0 = bf2f((u16)(v.x & 0xffff)); a1 = bf2f((u16)(v.x >> 16));
        a2 = bf2f((u16)(v.y & 0xffff)); a3 = bf2f((u16)(v.y >> 16));
    }
    int p = rp[row] + half, p1 = rp[row + 1];
    for (; p + 6 < p1; p += 8) {
        int s0 = col[p], s1 = col[p + 2], s2 = col[p + 4], s3 = col[p + 6];
        uint2 v0 = *(const uint2*)(xb + (size_t)s0 * FIN + fb);
        uint2 v1 = *(const uint2*)(xb + (size_t)s1 * FIN + fb);
        uint2 v2 = *(const uint2*)(xb + (size_t)s2 * FIN + fb);
        uint2 v3 = *(const uint2*)(xb + (size_t)s3 * FIN + fb);
        a0 += bf2f((u16)(v0.x & 0xffff)) + bf2f((u16)(v1.x & 0xffff))
            + bf2f((u16)(v2.x & 0xffff)) + bf2f((u16)(v3.x & 0xffff));
        a1 += bf2f((u16)(v0.x >> 16)) + bf2f((u16)(v1.x >> 16))
            + bf2f((u16)(v2.x >> 16)) + bf2f((u16)(v3.x >> 16));
        a2 += bf2f((u16)(v0.y & 0xffff)) + bf2f((u16)(v1.y & 0xffff))
            + bf2f((u16)(v2.y & 0xffff)) + bf2f((u16)(v3.y & 0xffff));
        a3 += bf2f((u16)(v0.y >> 16)) + bf2f((u16)(v1.y >> 16))
            + bf2f((u16)(v2.y >> 16)) + bf2f((u16)(v3.y >> 16));
    }
    for (; p < p1; p += 2) {
        int s = col[p];
        uint2 v = *(const uint2*)(xb + (size_t)s * FIN + fb);
        a0 += bf2f((u16)(v.x & 0xffff)); a1 += bf2f((u16)(v.x >> 16));
        a2 += bf2f((u16)(v.y & 0xffff)); a3 += bf2f((u16)(v.y >> 16));
    }
    a0 += __shfl_xor(a0, 32); a1 += __shfl_xor(a1, 32);
    a2 += __shfl_xor(a2, 32); a3 += __shfl_xor(a3, 32);
    if (half == 0) {
        uint2 o;
        o.x = (uint32_t)f2bf(a0) | ((uint32_t)f2bf(a1) << 16);
        o.y = (uint32_t)f2bf(a2) | ((uint32_t)f2bf(a3) << 16);
        *(uint2*)(out + (size_t)row * FIN + fb) = o;
    }
}

// ---------------- last layer: hs padded to 64 cols; agg + bias + log_softmax ----------------
__global__ __launch_bounds__(256) void k_agg5(const u16* __restrict__ hs,
                                              const int* __restrict__ rp,
                                              const int* __restrict__ col,
                                              const float* __restrict__ dinv,
                                              const u16* __restrict__ bias,
                                              void* __restrict__ out,
                                              const int* __restrict__ flags) {
    int row = blockIdx.x * 4 + (threadIdx.x >> 6);
    if (row >= NN) return;
    int lane = threadIdx.x & 63;
    int half = lane >> 5;
    int cl2 = lane & 31;
    float a0 = 0.f, a1 = 0.f;
    if (half == 0) {
        uint32_t v = *(const uint32_t*)(hs + (size_t)row * 64 + 2 * cl2);
        a0 = bf2f((u16)(v & 0xffff)); a1 = bf2f((u16)(v >> 16));
    }
    int p = rp[row] + half, p1 = rp[row + 1];
    for (; p + 6 < p1; p += 8) {
        int s0 = col[p], s1 = col[p + 2], s2 = col[p + 4], s3 = col[p + 6];
        uint32_t v0 = *(const uint32_t*)(hs + (size_t)s0 * 64 + 2 * cl2);
        uint32_t v1 = *(const uint32_t*)(hs + (size_t)s1 * 64 + 2 * cl2);
        uint32_t v2 = *(const uint32_t*)(hs + (size_t)s2 * 64 + 2 * cl2);
        uint32_t v3 = *(const uint32_t*)(hs + (size_t)s3 * 64 + 2 * cl2);
        a0 += bf2f((u16)(v0 & 0xffff)) + bf2f((u16)(v1 & 0xffff))
            + bf2f((u16)(v2 & 0xffff)) + bf2f((u16)(v3 & 0xffff));
        a1 += bf2f((u16)(v0 >> 16)) + bf2f((u16)(v1 >> 16))
            + bf2f((u16)(v2 >> 16)) + bf2f((u16)(v3 >> 16));
    }
    for (; p < p1; p += 2) {
        int s = col[p];
        uint32_t v = *(const uint32_t*)(hs + (size_t)s * 64 + 2 * cl2);
        a0 += bf2f((u16)(v & 0xffff));
        a1 += bf2f((u16)(v >> 16));
    }
    a0 += __shfl_xor(a0, 32);
    a1 += __shfl_xor(a1, 32);
    bool act = cl2 < (NCLS / 2);
    float d = dinv[row];
    uint32_t bv = *(const uint32_t*)(bias + 2 * cl2);
    float l0 = act ? fmaf(d, a0, bf2f((u16)(bv & 0xffff))) : -1e30f;
    float l1 = act ? fmaf(d, a1, bf2f((u16)(bv >> 16))) : -1e30f;
    float m = fmaxf(l0, l1);
#pragma unroll
    for (int off = 16; off > 0; off >>= 1) m = fmaxf(m, __shfl_xor(m, off));
    float e = act ? (__expf(l0 - m) + __expf(l1 - m)) : 0.f;
    float ss = e;
#pragma unroll
    for (int off = 16; off > 0; off >>= 1) ss += __shfl_xor(ss, off);
    if (act && half == 0) {
        float lg = __logf(ss);
        float r0 = l0 - m - lg, r1 = l1 - m - lg;
        if (flags[0]) {
            float* o = (float*)out + (size_t)row * NCLS + 2 * cl2;
            o[0] = r0; o[1] = r1;
        } else {
            uint32_t pk = (uint32_t)f2bf(r0) | ((uint32_t)f2bf(r1) << 16);
            *(uint32_t*)((u16*)out + (size_t)row * NCLS + 2 * cl2) = pk;
        }
    }
}

// ---------------- launch ----------------

extern "C" void kernel_launch(void* const* d_in, const int* in_sizes, int n_in,
                              void* d_out, int out_size, void* d_ws, size_t ws_size,
                              hipStream_t stream) {
    const void* x  = d_in[0];
    const int* ei  = (const int*)d_in[1];
    const void* W1 = d_in[2];
    const void* b1 = d_in[3];
    const void* W2 = d_in[4];
    const void* b2 = d_in[5];
    const void* W3 = d_in[6];
    const void* b3 = d_in[7];
    const void* W4 = d_in[8];
    const void* b4 = d_in[9];

    char* p = (char*)d_ws;
    auto alloc = [&](size_t b) -> char* {
        char* r = p;
        p += (b + 255) & ~(size_t)255;
        return r;
    };
    int*   flags = (int*)alloc(256);
    int*   cnt  = (int*)alloc((size_t)NN * 4);
    float* dinv = (float*)alloc((size_t)NN * 4);
    int*   rp   = (int*)alloc((size_t)(NN + 1) * 4);
    int*   col  = (int*)alloc((size_t)NE * 4);
    int*   bsum = (int*)alloc(4096);
    u16* xb  = (u16*)alloc((size_t)NN * FIN * 2);
    u16* W1t = (u16*)alloc((size_t)256 * 128 * 2);
    u16* W2t = (u16*)alloc((size_t)256 * 256 * 2);
    u16* W3t = (u16*)alloc((size_t)256 * 256 * 2);
    u16* W4t = (u16*)alloc((size_t)64 * 256 * 2);
    u16* bb1 = (u16*)alloc(512);
    u16* bb2 = (u16*)alloc(512);
    u16* bb3 = (u16*)alloc(512);
    u16* bb4 = (u16*)alloc(128);
    u16* bufA = (u16*)alloc((size_t)NN * HIDDEN * 2);
    u16* bufB = (u16*)alloc((size_t)NN * HIDDEN * 2);

    // CSR-build scratch aliased into bufB (used strictly before any conv)
    int* partial = (int*)bufB;                    // PRNG*SSL*RNG*4 = 12.8 MB

    k_detect<<<1, 256, 0, stream>>>((const u16*)x, ei, flags);

    // CSR build (atomic-free at device scope)
    k_histb<<<PRNG * SSL, 256, 0, stream>>>(ei, partial, flags);
    k_scan1<<<(NN + 1023) / 1024, 256, 0, stream>>>(partial, cnt, rp, bsum);
    k_scan2<<<1, 64, 0, stream>>>(bsum, (NN + 1023) / 1024);
    k_scan3o<<<(NN + 255) / 256, 256, 0, stream>>>(rp, bsum, cnt, dinv, partial);
    k_fillb<<<PRNG * SSL, 256, 0, stream>>>(ei, partial, col, flags);

    // inputs/weights to bf16 (x prescaled by dinv)
    k_cvt_x<<<(NN * FIN + 255) / 256, 256, 0, stream>>>(x, dinv, xb, flags);
    k_transpose_all<<<705, 256, 0, stream>>>(W1, W2, W3, W4, W1t, W2t, W3t, W4t,
                                             b1, b2, b3, b4, bb1, bb2, bb3, bb4, flags);

    dim3 gP(256, 2);
    dim3 aggGrid((NN + 3) / 4);

    // conv1 (aggregate-then-transform): y = A_hat_scaled @ xb; h1 = relu(dinv*(y W1) + b1)
    k_aggx<<<aggGrid, 256, 0, stream>>>(xb, rp, col, bufB);
    k_gemmP<<<gP, 256, 0, stream>>>(bufB, W1t, dinv, bb1, bufA, 128);
    // conv2: @ W2
    k_gemmP<<<gP, 256, 0, stream>>>(bufA, W2t, dinv, nullptr, bufB, 256);
    k_agg<<<aggGrid, 256, 0, stream>>>(bufB, rp, col, dinv, bb2, bufA);
    // conv3: @ W2 (reused)
    k_gemmP<<<gP, 256, 0, stream>>>(bufA, W2t, dinv, nullptr, bufB, 256);
    k_agg<<<aggGrid, 256, 0, stream>>>(bufB, rp, col, dinv, bb2, bufA);
    // conv4: @ W3
    k_gemmP<<<gP, 256, 0, stream>>>(bufA, W3t, dinv, nullptr, bufB, 256);
    k_agg<<<aggGrid, 256, 0, stream>>>(bufB, rp, col, dinv, bb3, bufA);
    // conv5: @ W4, padded to 64 cols, + fused log_softmax
    dim3 g64((NN + 63) / 64, 1);
    k_gemm64<<<g64, 256, 0, stream>>>(bufA, W4t, dinv, bufB, 256, 64);
    k_agg5<<<aggGrid, 256, 0, stream>>>(bufB, rp, col, dinv, bb4, d_out, flags);
}

// Round 10
// 946.806 us; speedup vs baseline: 1.3288x; 1.0200x over previous
//
#include <hip/hip_runtime.h>
#include <stdint.h>
#include <math.h>

#define NN   100000
#define FIN  128
#define HIDDEN 256
#define NCLS 40
#define NE   1600000

// CSR bucketing: P node-ranges x S edge-slices
#define PRNG 8
#define RNG  12500          // NN / PRNG
#define SSL  32
#define NES  50000          // NE / SSL

typedef unsigned short u16;
typedef __attribute__((ext_vector_type(8))) short s16x8;
typedef __attribute__((ext_vector_type(4))) float f32x4;

__device__ __forceinline__ float bf2f(unsigned short u) {
    union { float f; uint32_t i; } v; v.i = ((uint32_t)u) << 16; return v.f;
}
__device__ __forceinline__ unsigned short f2bf(float f) {
    union { float f; uint32_t i; } v; v.f = f;
    uint32_t r = v.i + 0x7fffu + ((v.i >> 16) & 1u);
    return (unsigned short)(r >> 16);
}

// ---------------- dtype detection ----------------
// flags[0] != 0 => float tensors are float32 (else bf16); flags[1] != 0 => edge_index int64
__global__ void k_detect(const u16* __restrict__ x16, const int* __restrict__ ei,
                         int* __restrict__ flags) {
    __shared__ int sh_nan, sh_odd;
    if (threadIdx.x == 0) { sh_nan = 0; sh_odd = 0; }
    __syncthreads();
    int t = threadIdx.x;
    int nan_cnt = 0;
    for (int i = t; i < 65536; i += 256) {
        u16 v = x16[i] & 0x7fff;
        if (v >= 0x7f80) nan_cnt++;
    }
    int odd_nz = 0;
    for (int i = t; i < 8192; i += 256) {
        if (ei[2 * i + 1] != 0) odd_nz++;
    }
    if (nan_cnt) atomicAdd(&sh_nan, nan_cnt);
    if (odd_nz) atomicAdd(&sh_odd, 1);
    __syncthreads();
    if (threadIdx.x == 0) {
        flags[0] = sh_nan;
        flags[1] = (sh_odd == 0) ? 1 : 0;
    }
}

// edge_index -> dense i32 dst/src (handles both i64 and i32 storage)
__global__ void k_compact(const int* __restrict__ ei, int* __restrict__ dst32,
                          int* __restrict__ src32, const int* __restrict__ flags) {
    int e = blockIdx.x * 256 + threadIdx.x;
    if (e < NE) {
        if (flags[1]) { src32[e] = ei[2 * e]; dst32[e] = ei[2 * (NE + e)]; }
        else          { src32[e] = ei[e];     dst32[e] = ei[NE + e]; }
    }
}

// weights transpose + bias cvt + x cvt (prescaled by dinv), all in one launch
__global__ void k_trans_cvt(const void* W1, const void* W2, const void* W3, const void* W4,
                            u16* W1t, u16* W2t, u16* W3t, u16* W4t,
                            const void* b1, const void* b2, const void* b3, const void* b4,
                            u16* o1, u16* o2, u16* o3, u16* o4,
                            const void* __restrict__ x, const float* __restrict__ dinv,
                            u16* __restrict__ xb,
                            const int* __restrict__ flags) {
    int b = blockIdx.x;
    int fl = flags[0];
    int t = threadIdx.x;
    if (b >= 705) {            // x convert: 50000 blocks
        int i = (b - 705) * 256 + t;
        if (i < NN * FIN) {
            float v = fl ? ((const float*)x)[i] : bf2f(((const u16*)x)[i]);
            xb[i] = f2bf(v * dinv[i >> 7]);
        }
        return;
    }
    if (b == 704) {
        o1[t] = fl ? f2bf(((const float*)b1)[t]) : ((const u16*)b1)[t];
        o2[t] = fl ? f2bf(((const float*)b2)[t]) : ((const u16*)b2)[t];
        o3[t] = fl ? f2bf(((const float*)b3)[t]) : ((const u16*)b3)[t];
        if (t < 64) o4[t] = (t < NCLS) ? (fl ? f2bf(((const float*)b4)[t]) : ((const u16*)b4)[t]) : (u16)0;
        return;
    }
    const void* W; u16* Wt; int K, F, Fpad, base;
    if (b < 128)      { W = W1; Wt = W1t; K = 128; F = 256; Fpad = 256; base = 0; }
    else if (b < 384) { W = W2; Wt = W2t; K = 256; F = 256; Fpad = 256; base = 128; }
    else if (b < 640) { W = W3; Wt = W3t; K = 256; F = 256; Fpad = 256; base = 384; }
    else              { W = W4; Wt = W4t; K = 256; F = 40;  Fpad = 64;  base = 640; }
    int idx = (b - base) * 256 + t;
    if (idx >= K * Fpad) return;
    int f = idx / K, k = idx - f * K;
    u16 v = 0;
    if (f < F) {
        if (fl) v = f2bf(((const float*)W)[(size_t)k * F + f]);
        else    v = ((const u16*)W)[(size_t)k * F + f];
    }
    Wt[idx] = v;
}

// ---------------- CSR build (no device atomics; i32 inputs) ----------------

__global__ __launch_bounds__(256) void k_histb(const int* __restrict__ dst32,
                                               int* __restrict__ partial) {
    __shared__ int h[RNG];
    int p = blockIdx.x >> 5, s = blockIdx.x & 31;
    int t = threadIdx.x;
    int4 z4 = make_int4(0, 0, 0, 0);
    for (int i = t * 4; i < RNG; i += 1024) *(int4*)(h + i) = z4;
    __syncthreads();
    int base = s * NES;
    int lo = p * RNG;
    int nfull = NES & ~1023;
    for (int k = t * 4; k < nfull; k += 1024) {
        int4 d4 = *(const int4*)(dst32 + base + k);
        int a;
        a = d4.x - lo; if ((unsigned)a < RNG) atomicAdd(&h[a], 1);
        a = d4.y - lo; if ((unsigned)a < RNG) atomicAdd(&h[a], 1);
        a = d4.z - lo; if ((unsigned)a < RNG) atomicAdd(&h[a], 1);
        a = d4.w - lo; if ((unsigned)a < RNG) atomicAdd(&h[a], 1);
    }
    for (int k = nfull + t; k < NES; k += 256) {
        int a = dst32[base + k] - lo;
        if ((unsigned)a < RNG) atomicAdd(&h[a], 1);
    }
    __syncthreads();
    int* out = partial + blockIdx.x * RNG;
    for (int i = t * 4; i < RNG; i += 1024) *(int4*)(out + i) = *(const int4*)(h + i);
}

// fused: per-node degree (sum of 32 partial slices) + block-local exclusive prefix
__global__ __launch_bounds__(256) void k_scan1(const int* __restrict__ partial,
                                               int* __restrict__ cnt,
                                               int* __restrict__ out,
                                               int* __restrict__ bsum) {
    __shared__ int sh[256];
    int t = threadIdx.x;
    int base = blockIdx.x * 1024 + t * 4;
    int v0 = 0, v1 = 0, v2 = 0, v3 = 0;
    if (base < NN) {
        int p = base / RNG, il = base - p * RNG;
        const int* q = partial + (p * SSL) * RNG + il;
        int4 acc = make_int4(0, 0, 0, 0);
#pragma unroll
        for (int s = 0; s < SSL; ++s) {
            int4 w = *(const int4*)(q + s * RNG);
            acc.x += w.x; acc.y += w.y; acc.z += w.z; acc.w += w.w;
        }
        v0 = acc.x; v1 = acc.y; v2 = acc.z; v3 = acc.w;
        *(int4*)(cnt + base) = acc;
    }
    int s = v0 + v1 + v2 + v3;
    sh[t] = s;
    __syncthreads();
    for (int off = 1; off < 256; off <<= 1) {
        int x = (t >= off) ? sh[t - off] : 0;
        __syncthreads();
        sh[t] += x;
        __syncthreads();
    }
    int ex = sh[t] - s;
    if (base < NN) {
        int4 o = make_int4(ex, ex + v0, ex + v0 + v1, ex + v0 + v1 + v2);
        *(int4*)(out + base) = o;
    }
    if (t == 255) bsum[blockIdx.x] = sh[255];
}

__global__ void k_scan2(int* bsum, int nb) {
    if (threadIdx.x == 0 && blockIdx.x == 0) {
        int run = 0;
        for (int i = 0; i < nb; ++i) { int t = bsum[i]; bsum[i] = run; run += t; }
    }
}

// finalize rp, dinv, and convert partial -> absolute slice offsets
__global__ void k_scan3o(int* __restrict__ rp, const int* __restrict__ bsum,
                         const int* __restrict__ cnt, float* __restrict__ dinv,
                         int* __restrict__ partial) {
    int i = blockIdx.x * 256 + threadIdx.x;
    if (i < NN) {
        int v = rp[i] + bsum[i >> 10];
        rp[i] = v;
        dinv[i] = rsqrtf((float)(cnt[i] + 1));
        int p = i / RNG, il = i - p * RNG;
        int* q = partial + (p * SSL) * RNG + il;
        int run = v;
#pragma unroll
        for (int s = 0; s < SSL; ++s) { int t = q[s * RNG]; q[s * RNG] = run; run += t; }
    }
    if (i == 0) rp[NN] = NE;
}

__global__ __launch_bounds__(256) void k_fillb(const int* __restrict__ dst32,
                                               const int* __restrict__ src32,
                                               const int* __restrict__ offs,
                                               int* __restrict__ col) {
    __shared__ int h[RNG];
    int p = blockIdx.x >> 5, s = blockIdx.x & 31;
    int t = threadIdx.x;
    const int* o = offs + blockIdx.x * RNG;
    for (int i = t * 4; i < RNG; i += 1024) *(int4*)(h + i) = *(const int4*)(o + i);
    __syncthreads();
    int base = s * NES;
    int lo = p * RNG;
    int nfull = NES & ~1023;
    for (int k = t * 4; k < nfull; k += 1024) {
        int4 d4 = *(const int4*)(dst32 + base + k);
        int4 s4 = *(const int4*)(src32 + base + k);
        int a;
        a = d4.x - lo; if ((unsigned)a < RNG) col[atomicAdd(&h[a], 1)] = s4.x;
        a = d4.y - lo; if ((unsigned)a < RNG) col[atomicAdd(&h[a], 1)] = s4.y;
        a = d4.z - lo; if ((unsigned)a < RNG) col[atomicAdd(&h[a], 1)] = s4.z;
        a = d4.w - lo; if ((unsigned)a < RNG) col[atomicAdd(&h[a], 1)] = s4.w;
    }
    for (int k = nfull + t; k < NES; k += 256) {
        int a = dst32[base + k] - lo;
        if ((unsigned)a < RNG) col[atomicAdd(&h[a], 1)] = src32[base + k];
    }
}

// ---------------- Persistent-B GEMM (N=256 halves): C = epi(A @ Wt^T) ----------------

#define GLL(g, l) __builtin_amdgcn_global_load_lds( \
    (const __attribute__((address_space(1))) unsigned int*)(g), \
    (__attribute__((address_space(3))) unsigned int*)(l), 16, 0, 0)

#define NT128 ((NN + 127) / 128)
#define NT256 ((NN + 255) / 256)

__global__ __launch_bounds__(256) void k_gemmP(const u16* __restrict__ A,
                                               const u16* __restrict__ Wt,
                                               const float* __restrict__ dinv,
                                               const u16* __restrict__ bias,
                                               u16* __restrict__ C,
                                               int K) {
    __shared__ __align__(16) u16 Bs[128 * 256];   // blocked [K/32][128][32]
    __shared__ __align__(16) u16 As[2 * 128 * 32];
    int t = threadIdx.x;
    int bn = blockIdx.y;
    int w = t >> 6, lane = t & 63;
    int wm = w >> 1, wn = w & 1;
    int lrow = lane & 15, lq = lane >> 4;
    int r0 = t >> 2;
    int seg = (t & 3) * 8;

    int rounds = K >> 4;
    for (int r = 0; r < rounds; ++r) {
        int d = r * 4096 + t * 16;
        int kt = d >> 13;
        int win = d & 8191;
        int row = win >> 6;
        int sg = (win & 63) >> 1;
        GLL(Wt + (size_t)(bn * 128 + row) * K + kt * 32 + sg, Bs + (d >> 1));
    }

    int nK = K >> 5;
    bool fuse = (bias != nullptr);
    float bcol[4];
#pragma unroll
    for (int j = 0; j < 4; ++j)
        bcol[j] = fuse ? bf2f(bias[bn * 128 + wn * 64 + j * 16 + lrow]) : 0.f;

    for (int tm = blockIdx.x; tm < NT128; tm += gridDim.x) {
        int rowBase = tm * 128;
        int ar0 = rowBase + r0;       if (ar0 > NN - 1) ar0 = NN - 1;
        int ar1 = rowBase + 64 + r0;  if (ar1 > NN - 1) ar1 = NN - 1;
        const u16* a0p = A + (size_t)ar0 * K + seg;
        const u16* a1p = A + (size_t)ar1 * K + seg;
        GLL(a0p, As + t * 8);
        GLL(a1p, As + 2048 + t * 8);

        f32x4 acc[4][4] = {};
        int cur = 0;
        for (int kt = 0; kt < nK; ++kt) {
            __syncthreads();
            if (kt + 1 < nK) {
                int nxt = cur ^ 1;
                GLL(a0p + (kt + 1) * 32, As + nxt * 4096 + t * 8);
                GLL(a1p + (kt + 1) * 32, As + nxt * 4096 + 2048 + t * 8);
            }
            const u16* ab = As + cur * 4096;
            const u16* bb = Bs + kt * 4096;
            s16x8 af[4], bf[4];
#pragma unroll
            for (int i = 0; i < 4; ++i)
                af[i] = *(const s16x8*)(ab + (wm * 64 + i * 16 + lrow) * 32 + lq * 8);
#pragma unroll
            for (int j = 0; j < 4; ++j)
                bf[j] = *(const s16x8*)(bb + (wn * 64 + j * 16 + lrow) * 32 + lq * 8);
#pragma unroll
            for (int i = 0; i < 4; ++i)
#pragma unroll
                for (int j = 0; j < 4; ++j)
                    acc[i][j] = __builtin_amdgcn_mfma_f32_16x16x32_bf16(af[i], bf[j], acc[i][j], 0, 0, 0);
            cur ^= 1;
        }

#pragma unroll
        for (int i = 0; i < 4; ++i) {
#pragma unroll
            for (int rr = 0; rr < 4; ++rr) {
                int row = rowBase + wm * 64 + i * 16 + lq * 4 + rr;
                if (row < NN) {
                    float d = dinv[row];
#pragma unroll
                    for (int j = 0; j < 4; ++j) {
                        int colg = bn * 128 + wn * 64 + j * 16 + lrow;
                        float v = fuse ? fmaxf(fmaf(d, acc[i][j][rr], bcol[j]), 0.f)
                                       : acc[i][j][rr] * d;
                        C[(size_t)row * HIDDEN + colg] = f2bf(v);
                    }
                }
            }
        }
        __syncthreads();
    }
}

// ---------------- Persistent-B GEMM conv5: 256-row x 64-col tiles, K=256 ----------------
// Bs = 64x256 blocked [8][64][32] (32 KB); As double-buffered 2x(256x32) (32 KB).
__global__ __launch_bounds__(256) void k_gemmP64(const u16* __restrict__ A,
                                                 const u16* __restrict__ Wt,
                                                 const float* __restrict__ dinv,
                                                 u16* __restrict__ C) {
    const int K = 256;
    __shared__ __align__(16) u16 Bs[64 * 256];
    __shared__ __align__(16) u16 As[2 * 256 * 32];
    int t = threadIdx.x;
    int w = t >> 6, lane = t & 63;
    int lrow = lane & 15, lq = lane >> 4;
    int seg = (t & 3) * 8;
    int rr0 = t >> 2;              // 0..63 row within chunk

    // B load once: 8 rounds of 4 KB; round r covers kt=r block [64][32]
    for (int r = 0; r < 8; ++r)
        GLL(Wt + (size_t)(t >> 2) * K + r * 32 + seg, Bs + r * 2048 + t * 8);

    for (int tm = blockIdx.x; tm < NT256; tm += gridDim.x) {
        int rowBase = tm * 256;
        const u16* ap[4];
#pragma unroll
        for (int c = 0; c < 4; ++c) {
            int ar = rowBase + c * 64 + rr0;
            if (ar > NN - 1) ar = NN - 1;
            ap[c] = A + (size_t)ar * K + seg;
        }
#pragma unroll
        for (int c = 0; c < 4; ++c) GLL(ap[c], As + c * 2048 + t * 8);

        f32x4 acc[4][4] = {};
        int cur = 0;
        for (int kt = 0; kt < 8; ++kt) {
            __syncthreads();
            if (kt + 1 < 8) {
                int nxt = cur ^ 1;
#pragma unroll
                for (int c = 0; c < 4; ++c)
                    GLL(ap[c] + (kt + 1) * 32, As + nxt * 8192 + c * 2048 + t * 8);
            }
            const u16* ab = As + cur * 8192;
            const u16* bb = Bs + kt * 2048;
            s16x8 af[4], bf[4];
#pragma unroll
            for (int i = 0; i < 4; ++i)
                af[i] = *(const s16x8*)(ab + (w * 64 + i * 16 + lrow) * 32 + lq * 8);
#pragma unroll
            for (int j = 0; j < 4; ++j)
                bf[j] = *(const s16x8*)(bb + (j * 16 + lrow) * 32 + lq * 8);
#pragma unroll
            for (int i = 0; i < 4; ++i)
#pragma unroll
                for (int j = 0; j < 4; ++j)
                    acc[i][j] = __builtin_amdgcn_mfma_f32_16x16x32_bf16(af[i], bf[j], acc[i][j], 0, 0, 0);
            cur ^= 1;
        }

#pragma unroll
        for (int i = 0; i < 4; ++i) {
#pragma unroll
            for (int rr = 0; rr < 4; ++rr) {
                int row = rowBase + w * 64 + i * 16 + lq * 4 + rr;
                if (row < NN) {
                    float d = dinv[row];
#pragma unroll
                    for (int j = 0; j < 4; ++j) {
                        int colg = j * 16 + lrow;
                        C[(size_t)row * 64 + colg] = f2bf(acc[i][j][rr] * d);
                    }
                }
            }
        }
        __syncthreads();
    }
}

// ---------------- aggregation F=256 (round-4 structure: best measured) ----------------

__device__ __forceinline__ void acc8(float* a, uint4 v) {
    a[0] += bf2f((u16)(v.x & 0xffff)); a[1] += bf2f((u16)(v.x >> 16));
    a[2] += bf2f((u16)(v.y & 0xffff)); a[3] += bf2f((u16)(v.y >> 16));
    a[4] += bf2f((u16)(v.z & 0xffff)); a[5] += bf2f((u16)(v.z >> 16));
    a[6] += bf2f((u16)(v.w & 0xffff)); a[7] += bf2f((u16)(v.w >> 16));
}

__global__ __launch_bounds__(256) void k_agg(const u16* __restrict__ hs,
                                             const int* __restrict__ rp,
                                             const int* __restrict__ col,
                                             const float* __restrict__ dinv,
                                             const u16* __restrict__ bias,
                                             u16* __restrict__ out) {
    int row = blockIdx.x * 4 + (threadIdx.x >> 6);
    if (row >= NN) return;
    int lane = threadIdx.x & 63;
    int half = lane >> 5;
    int fb = (lane & 31) * 8;
    float a[8] = {0.f, 0.f, 0.f, 0.f, 0.f, 0.f, 0.f, 0.f};
    if (half == 0) acc8(a, *(const uint4*)(hs + (size_t)row * HIDDEN + fb));
    int p = rp[row] + half, p1 = rp[row + 1];
    for (; p + 6 < p1; p += 8) {
        int s0 = col[p], s1 = col[p + 2], s2 = col[p + 4], s3 = col[p + 6];
        uint4 v0 = *(const uint4*)(hs + (size_t)s0 * HIDDEN + fb);
        uint4 v1 = *(const uint4*)(hs + (size_t)s1 * HIDDEN + fb);
        uint4 v2 = *(const uint4*)(hs + (size_t)s2 * HIDDEN + fb);
        uint4 v3 = *(const uint4*)(hs + (size_t)s3 * HIDDEN + fb);
        acc8(a, v0);
        acc8(a, v1);
        acc8(a, v2);
        acc8(a, v3);
    }
    for (; p < p1; p += 2) {
        int s = col[p];
        acc8(a, *(const uint4*)(hs + (size_t)s * HIDDEN + fb));
    }
#pragma unroll
    for (int i = 0; i < 8; ++i) a[i] += __shfl_xor(a[i], 32);
    if (half == 0) {
        float d = dinv[row];
        uint4 bv = *(const uint4*)(bias + fb);
        float r0 = fmaxf(fmaf(d, a[0], bf2f((u16)(bv.x & 0xffff))), 0.f);
        float r1 = fmaxf(fmaf(d, a[1], bf2f((u16)(bv.x >> 16))), 0.f);
        float r2 = fmaxf(fmaf(d, a[2], bf2f((u16)(bv.y & 0xffff))), 0.f);
        float r3 = fmaxf(fmaf(d, a[3], bf2f((u16)(bv.y >> 16))), 0.f);
        float r4 = fmaxf(fmaf(d, a[4], bf2f((u16)(bv.z & 0xffff))), 0.f);
        float r5 = fmaxf(fmaf(d, a[5], bf2f((u16)(bv.z >> 16))), 0.f);
        float r6 = fmaxf(fmaf(d, a[6], bf2f((u16)(bv.w & 0xffff))), 0.f);
        float r7 = fmaxf(fmaf(d, a[7], bf2f((u16)(bv.w >> 16))), 0.f);
        uint4 o;
        o.x = (uint32_t)f2bf(r0) | ((uint32_t)f2bf(r1) << 16);
        o.y = (uint32_t)f2bf(r2) | ((uint32_t)f2bf(r3) << 16);
        o.z = (uint32_t)f2bf(r4) | ((uint32_t)f2bf(r5) << 16);
        o.w = (uint32_t)f2bf(r6) | ((uint32_t)f2bf(r7) << 16);
        *(uint4*)(out + (size_t)row * HIDDEN + fb) = o;
    }
}

// ---------------- conv1 pre-aggregation on prescaled x (128 features) ----------------
__global__ __launch_bounds__(256) void k_aggx(const u16* __restrict__ xb,
                                              const int* __restrict__ rp,
                                              const int* __restrict__ col,
                                              u16* __restrict__ out) {
    int row = blockIdx.x * 4 + (threadIdx.x >> 6);
    if (row >= NN) return;
    int lane = threadIdx.x & 63;
    int half = lane >> 5;
    int fb = (lane & 31) * 4;
    float a0 = 0.f, a1 = 0.f, a2 = 0.f, a3 = 0.f;
    if (half == 0) {
        uint2 v = *(const uint2*)(xb + (size_t)row * FIN + fb);
        a0 = bf2f((u16)(v.x & 0xffff)); a1 = bf2f((u16)(v.x >> 16));
        a2 = bf2f((u16)(v.y & 0xffff)); a3 = bf2f((u16)(v.y >> 16));
    }
    int p = rp[row] + half, p1 = rp[row + 1];
    for (; p + 6 < p1; p += 8) {
        int s0 = col[p], s1 = col[p + 2], s2 = col[p + 4], s3 = col[p + 6];
        uint2 v0 = *(const uint2*)(xb + (size_t)s0 * FIN + fb);
        uint2 v1 = *(const uint2*)(xb + (size_t)s1 * FIN + fb);
        uint2 v2 = *(const uint2*)(xb + (size_t)s2 * FIN + fb);
        uint2 v3 = *(const uint2*)(xb + (size_t)s3 * FIN + fb);
        a0 += bf2f((u16)(v0.x & 0xffff)) + bf2f((u16)(v1.x & 0xffff))
            + bf2f((u16)(v2.x & 0xffff)) + bf2f((u16)(v3.x & 0xffff));
        a1 += bf2f((u16)(v0.x >> 16)) + bf2f((u16)(v1.x >> 16))
            + bf2f((u16)(v2.x >> 16)) + bf2f((u16)(v3.x >> 16));
        a2 += bf2f((u16)(v0.y & 0xffff)) + bf2f((u16)(v1.y & 0xffff))
            + bf2f((u16)(v2.y & 0xffff)) + bf2f((u16)(v3.y & 0xffff));
        a3 += bf2f((u16)(v0.y >> 16)) + bf2f((u16)(v1.y >> 16))
            + bf2f((u16)(v2.y >> 16)) + bf2f((u16)(v3.y >> 16));
    }
    for (; p < p1; p += 2) {
        int s = col[p];
        uint2 v = *(const uint2*)(xb + (size_t)s * FIN + fb);
        a0 += bf2f((u16)(v.x & 0xffff)); a1 += bf2f((u16)(v.x >> 16));
        a2 += bf2f((u16)(v.y & 0xffff)); a3 += bf2f((u16)(v.y >> 16));
    }
    a0 += __shfl_xor(a0, 32); a1 += __shfl_xor(a1, 32);
    a2 += __shfl_xor(a2, 32); a3 += __shfl_xor(a3, 32);
    if (half == 0) {
        uint2 o;
        o.x = (uint32_t)f2bf(a0) | ((uint32_t)f2bf(a1) << 16);
        o.y = (uint32_t)f2bf(a2) | ((uint32_t)f2bf(a3) << 16);
        *(uint2*)(out + (size_t)row * FIN + fb) = o;
    }
}

// ---------------- last layer: hs padded to 64 cols; agg + bias + log_softmax ----------------
__global__ __launch_bounds__(256) void k_agg5(const u16* __restrict__ hs,
                                              const int* __restrict__ rp,
                                              const int* __restrict__ col,
                                              const float* __restrict__ dinv,
                                              const u16* __restrict__ bias,
                                              void* __restrict__ out,
                                              const int* __restrict__ flags) {
    int row = blockIdx.x * 4 + (threadIdx.x >> 6);
    if (row >= NN) return;
    int lane = threadIdx.x & 63;
    int half = lane >> 5;
    int cl2 = lane & 31;
    float a0 = 0.f, a1 = 0.f;
    if (half == 0) {
        uint32_t v = *(const uint32_t*)(hs + (size_t)row * 64 + 2 * cl2);
        a0 = bf2f((u16)(v & 0xffff)); a1 = bf2f((u16)(v >> 16));
    }
    int p = rp[row] + half, p1 = rp[row + 1];
    for (; p + 6 < p1; p += 8) {
        int s0 = col[p], s1 = col[p + 2], s2 = col[p + 4], s3 = col[p + 6];
        uint32_t v0 = *(const uint32_t*)(hs + (size_t)s0 * 64 + 2 * cl2);
        uint32_t v1 = *(const uint32_t*)(hs + (size_t)s1 * 64 + 2 * cl2);
        uint32_t v2 = *(const uint32_t*)(hs + (size_t)s2 * 64 + 2 * cl2);
        uint32_t v3 = *(const uint32_t*)(hs + (size_t)s3 * 64 + 2 * cl2);
        a0 += bf2f((u16)(v0 & 0xffff)) + bf2f((u16)(v1 & 0xffff))
            + bf2f((u16)(v2 & 0xffff)) + bf2f((u16)(v3 & 0xffff));
        a1 += bf2f((u16)(v0 >> 16)) + bf2f((u16)(v1 >> 16))
            + bf2f((u16)(v2 >> 16)) + bf2f((u16)(v3 >> 16));
    }
    for (; p < p1; p += 2) {
        int s = col[p];
        uint32_t v = *(const uint32_t*)(hs + (size_t)s * 64 + 2 * cl2);
        a0 += bf2f((u16)(v & 0xffff));
        a1 += bf2f((u16)(v >> 16));
    }
    a0 += __shfl_xor(a0, 32);
    a1 += __shfl_xor(a1, 32);
    bool act = cl2 < (NCLS / 2);
    float d = dinv[row];
    uint32_t bv = *(const uint32_t*)(bias + 2 * cl2);
    float l0 = act ? fmaf(d, a0, bf2f((u16)(bv & 0xffff))) : -1e30f;
    float l1 = act ? fmaf(d, a1, bf2f((u16)(bv >> 16))) : -1e30f;
    float m = fmaxf(l0, l1);
#pragma unroll
    for (int off = 16; off > 0; off >>= 1) m = fmaxf(m, __shfl_xor(m, off));
    float e = act ? (__expf(l0 - m) + __expf(l1 - m)) : 0.f;
    float ss = e;
#pragma unroll
    for (int off = 16; off > 0; off >>= 1) ss += __shfl_xor(ss, off);
    if (act && half == 0) {
        float lg = __logf(ss);
        float r0 = l0 - m - lg, r1 = l1 - m - lg;
        if (flags[0]) {
            float* o = (float*)out + (size_t)row * NCLS + 2 * cl2;
            o[0] = r0; o[1] = r1;
        } else {
            uint32_t pk = (uint32_t)f2bf(r0) | ((uint32_t)f2bf(r1) << 16);
            *(uint32_t*)((u16*)out + (size_t)row * NCLS + 2 * cl2) = pk;
        }
    }
}

// ---------------- launch ----------------

extern "C" void kernel_launch(void* const* d_in, const int* in_sizes, int n_in,
                              void* d_out, int out_size, void* d_ws, size_t ws_size,
                              hipStream_t stream) {
    const void* x  = d_in[0];
    const int* ei  = (const int*)d_in[1];
    const void* W1 = d_in[2];
    const void* b1 = d_in[3];
    const void* W2 = d_in[4];
    const void* b2 = d_in[5];
    const void* W3 = d_in[6];
    const void* b3 = d_in[7];
    const void* W4 = d_in[8];
    const void* b4 = d_in[9];

    char* p = (char*)d_ws;
    auto alloc = [&](size_t b) -> char* {
        char* r = p;
        p += (b + 255) & ~(size_t)255;
        return r;
    };
    int*   flags = (int*)alloc(256);
    int*   cnt  = (int*)alloc((size_t)NN * 4);
    float* dinv = (float*)alloc((size_t)NN * 4);
    int*   rp   = (int*)alloc((size_t)(NN + 1) * 4);
    int*   col  = (int*)alloc((size_t)NE * 4);
    int*   bsum = (int*)alloc(4096);
    u16* xb  = (u16*)alloc((size_t)NN * FIN * 2);
    u16* W1t = (u16*)alloc((size_t)256 * 128 * 2);
    u16* W2t = (u16*)alloc((size_t)256 * 256 * 2);
    u16* W3t = (u16*)alloc((size_t)256 * 256 * 2);
    u16* W4t = (u16*)alloc((size_t)64 * 256 * 2);
    u16* bb1 = (u16*)alloc(512);
    u16* bb2 = (u16*)alloc(512);
    u16* bb3 = (u16*)alloc(512);
    u16* bb4 = (u16*)alloc(128);
    u16* bufA = (u16*)alloc((size_t)NN * HIDDEN * 2);
    u16* bufB = (u16*)alloc((size_t)NN * HIDDEN * 2);

    // CSR-build scratch aliased into conv buffers (dead before conv use)
    int* dst32   = (int*)bufA;                    // 6.4 MB
    int* src32   = dst32 + NE;                    // 6.4 MB
    int* partial = (int*)bufB;                    // 12.8 MB

    k_detect<<<1, 256, 0, stream>>>((const u16*)x, ei, flags);
    k_compact<<<(NE + 255) / 256, 256, 0, stream>>>(ei, dst32, src32, flags);

    // CSR build (atomic-free at device scope, i32 streams)
    k_histb<<<PRNG * SSL, 256, 0, stream>>>(dst32, partial);
    k_scan1<<<(NN + 1023) / 1024, 256, 0, stream>>>(partial, cnt, rp, bsum);
    k_scan2<<<1, 64, 0, stream>>>(bsum, (NN + 1023) / 1024);
    k_scan3o<<<(NN + 255) / 256, 256, 0, stream>>>(rp, bsum, cnt, dinv, partial);
    k_fillb<<<PRNG * SSL, 256, 0, stream>>>(dst32, src32, partial, col);

    // weights/bias transpose + x convert (prescaled by dinv), one launch
    k_trans_cvt<<<705 + (NN * FIN + 255) / 256, 256, 0, stream>>>(
        W1, W2, W3, W4, W1t, W2t, W3t, W4t,
        b1, b2, b3, b4, bb1, bb2, bb3, bb4, x, dinv, xb, flags);

    dim3 gP(256, 2);
    dim3 aggGrid((NN + 3) / 4);

    // conv1 (aggregate-then-transform): y = A_hat_scaled @ xb; h1 = relu(dinv*(y W1) + b1)
    k_aggx<<<aggGrid, 256, 0, stream>>>(xb, rp, col, bufB);
    k_gemmP<<<gP, 256, 0, stream>>>(bufB, W1t, dinv, bb1, bufA, 128);
    // conv2: @ W2
    k_gemmP<<<gP, 256, 0, stream>>>(bufA, W2t, dinv, nullptr, bufB, 256);
    k_agg<<<aggGrid, 256, 0, stream>>>(bufB, rp, col, dinv, bb2, bufA);
    // conv3: @ W2 (reused)
    k_gemmP<<<gP, 256, 0, stream>>>(bufA, W2t, dinv, nullptr, bufB, 256);
    k_agg<<<aggGrid, 256, 0, stream>>>(bufB, rp, col, dinv, bb2, bufA);
    // conv4: @ W3
    k_gemmP<<<gP, 256, 0, stream>>>(bufA, W3t, dinv, nullptr, bufB, 256);
    k_agg<<<aggGrid, 256, 0, stream>>>(bufB, rp, col, dinv, bb3, bufA);
    // conv5: @ W4 (persistent-B, padded to 64 cols) + fused log_softmax
    k_gemmP64<<<256, 256, 0, stream>>>(bufA, W4t, dinv, bufB);
    k_agg5<<<aggGrid, 256, 0, stream>>>(bufB, rp, col, dinv, bb4, d_out, flags);
}

// Round 11
// 814.561 us; speedup vs baseline: 1.5446x; 1.1624x over previous
//
#include <hip/hip_runtime.h>
#include <stdint.h>
#include <math.h>

#define NN   100000
#define FIN  128
#define HIDDEN 256
#define NCLS 40
#define NE   1600000

// CSR bucketing: P node-ranges x S edge-slices
#define PRNG 8
#define RNG  12500          // NN / PRNG
#define SSL  32
#define NES  50000          // NE / SSL

typedef unsigned short u16;
typedef unsigned char u8;
typedef __attribute__((ext_vector_type(8))) short s16x8;
typedef __attribute__((ext_vector_type(4))) float f32x4;
typedef __attribute__((ext_vector_type(2))) float f32x2;

__device__ __forceinline__ float bf2f(unsigned short u) {
    union { float f; uint32_t i; } v; v.i = ((uint32_t)u) << 16; return v.f;
}
__device__ __forceinline__ unsigned short f2bf(float f) {
    union { float f; uint32_t i; } v; v.f = f;
    uint32_t r = v.i + 0x7fffu + ((v.i >> 16) & 1u);
    return (unsigned short)(r >> 16);
}
__device__ __forceinline__ u8 f2fp8(float f) {
    int r = __builtin_amdgcn_cvt_pk_fp8_f32(f, f, 0, false);
    return (u8)(r & 0xff);
}

// ---------------- dtype detection ----------------
// flags[0] != 0 => float tensors are float32 (else bf16); flags[1] != 0 => edge_index int64
__global__ void k_detect(const u16* __restrict__ x16, const int* __restrict__ ei,
                         int* __restrict__ flags) {
    __shared__ int sh_nan, sh_odd;
    if (threadIdx.x == 0) { sh_nan = 0; sh_odd = 0; }
    __syncthreads();
    int t = threadIdx.x;
    int nan_cnt = 0;
    for (int i = t; i < 65536; i += 256) {
        u16 v = x16[i] & 0x7fff;
        if (v >= 0x7f80) nan_cnt++;
    }
    int odd_nz = 0;
    for (int i = t; i < 8192; i += 256) {
        if (ei[2 * i + 1] != 0) odd_nz++;
    }
    if (nan_cnt) atomicAdd(&sh_nan, nan_cnt);
    if (odd_nz) atomicAdd(&sh_odd, 1);
    __syncthreads();
    if (threadIdx.x == 0) {
        flags[0] = sh_nan;
        flags[1] = (sh_odd == 0) ? 1 : 0;
    }
}

// edge_index -> dense i32 dst/src (handles both i64 and i32 storage)
__global__ void k_compact(const int* __restrict__ ei, int* __restrict__ dst32,
                          int* __restrict__ src32, const int* __restrict__ flags) {
    int e = blockIdx.x * 256 + threadIdx.x;
    if (e < NE) {
        if (flags[1]) { src32[e] = ei[2 * e]; dst32[e] = ei[2 * (NE + e)]; }
        else          { src32[e] = ei[e];     dst32[e] = ei[NE + e]; }
    }
}

// weights transpose + bias cvt + x cvt (prescaled by dinv), all in one launch
__global__ void k_trans_cvt(const void* W1, const void* W2, const void* W3, const void* W4,
                            u16* W1t, u16* W2t, u16* W3t, u16* W4t,
                            const void* b1, const void* b2, const void* b3, const void* b4,
                            u16* o1, u16* o2, u16* o3, u16* o4,
                            const void* __restrict__ x, const float* __restrict__ dinv,
                            u16* __restrict__ xb,
                            const int* __restrict__ flags) {
    int b = blockIdx.x;
    int fl = flags[0];
    int t = threadIdx.x;
    if (b >= 705) {            // x convert: 50000 blocks
        int i = (b - 705) * 256 + t;
        if (i < NN * FIN) {
            float v = fl ? ((const float*)x)[i] : bf2f(((const u16*)x)[i]);
            xb[i] = f2bf(v * dinv[i >> 7]);
        }
        return;
    }
    if (b == 704) {
        o1[t] = fl ? f2bf(((const float*)b1)[t]) : ((const u16*)b1)[t];
        o2[t] = fl ? f2bf(((const float*)b2)[t]) : ((const u16*)b2)[t];
        o3[t] = fl ? f2bf(((const float*)b3)[t]) : ((const u16*)b3)[t];
        if (t < 64) o4[t] = (t < NCLS) ? (fl ? f2bf(((const float*)b4)[t]) : ((const u16*)b4)[t]) : (u16)0;
        return;
    }
    const void* W; u16* Wt; int K, F, Fpad, base;
    if (b < 128)      { W = W1; Wt = W1t; K = 128; F = 256; Fpad = 256; base = 0; }
    else if (b < 384) { W = W2; Wt = W2t; K = 256; F = 256; Fpad = 256; base = 128; }
    else if (b < 640) { W = W3; Wt = W3t; K = 256; F = 256; Fpad = 256; base = 384; }
    else              { W = W4; Wt = W4t; K = 256; F = 40;  Fpad = 64;  base = 640; }
    int idx = (b - base) * 256 + t;
    if (idx >= K * Fpad) return;
    int f = idx / K, k = idx - f * K;
    u16 v = 0;
    if (f < F) {
        if (fl) v = f2bf(((const float*)W)[(size_t)k * F + f]);
        else    v = ((const u16*)W)[(size_t)k * F + f];
    }
    Wt[idx] = v;
}

// ---------------- CSR build (no device atomics; i32 inputs) ----------------

__global__ __launch_bounds__(256) void k_histb(const int* __restrict__ dst32,
                                               int* __restrict__ partial) {
    __shared__ int h[RNG];
    int p = blockIdx.x >> 5, s = blockIdx.x & 31;
    int t = threadIdx.x;
    int4 z4 = make_int4(0, 0, 0, 0);
    for (int i = t * 4; i < RNG; i += 1024) *(int4*)(h + i) = z4;
    __syncthreads();
    int base = s * NES;
    int lo = p * RNG;
    int nfull = NES & ~1023;
    for (int k = t * 4; k < nfull; k += 1024) {
        int4 d4 = *(const int4*)(dst32 + base + k);
        int a;
        a = d4.x - lo; if ((unsigned)a < RNG) atomicAdd(&h[a], 1);
        a = d4.y - lo; if ((unsigned)a < RNG) atomicAdd(&h[a], 1);
        a = d4.z - lo; if ((unsigned)a < RNG) atomicAdd(&h[a], 1);
        a = d4.w - lo; if ((unsigned)a < RNG) atomicAdd(&h[a], 1);
    }
    for (int k = nfull + t; k < NES; k += 256) {
        int a = dst32[base + k] - lo;
        if ((unsigned)a < RNG) atomicAdd(&h[a], 1);
    }
    __syncthreads();
    int* out = partial + blockIdx.x * RNG;
    for (int i = t * 4; i < RNG; i += 1024) *(int4*)(out + i) = *(const int4*)(h + i);
}

// fused: per-node degree (sum of 32 partial slices) + block-local exclusive prefix
__global__ __launch_bounds__(256) void k_scan1(const int* __restrict__ partial,
                                               int* __restrict__ cnt,
                                               int* __restrict__ out,
                                               int* __restrict__ bsum) {
    __shared__ int sh[256];
    int t = threadIdx.x;
    int base = blockIdx.x * 1024 + t * 4;
    int v0 = 0, v1 = 0, v2 = 0, v3 = 0;
    if (base < NN) {
        int p = base / RNG, il = base - p * RNG;
        const int* q = partial + (p * SSL) * RNG + il;
        int4 acc = make_int4(0, 0, 0, 0);
#pragma unroll
        for (int s = 0; s < SSL; ++s) {
            int4 w = *(const int4*)(q + s * RNG);
            acc.x += w.x; acc.y += w.y; acc.z += w.z; acc.w += w.w;
        }
        v0 = acc.x; v1 = acc.y; v2 = acc.z; v3 = acc.w;
        *(int4*)(cnt + base) = acc;
    }
    int s = v0 + v1 + v2 + v3;
    sh[t] = s;
    __syncthreads();
    for (int off = 1; off < 256; off <<= 1) {
        int x = (t >= off) ? sh[t - off] : 0;
        __syncthreads();
        sh[t] += x;
        __syncthreads();
    }
    int ex = sh[t] - s;
    if (base < NN) {
        int4 o = make_int4(ex, ex + v0, ex + v0 + v1, ex + v0 + v1 + v2);
        *(int4*)(out + base) = o;
    }
    if (t == 255) bsum[blockIdx.x] = sh[255];
}

__global__ void k_scan2(int* bsum, int nb) {
    if (threadIdx.x == 0 && blockIdx.x == 0) {
        int run = 0;
        for (int i = 0; i < nb; ++i) { int t = bsum[i]; bsum[i] = run; run += t; }
    }
}

// finalize rp, dinv, and convert partial -> absolute slice offsets
__global__ void k_scan3o(int* __restrict__ rp, const int* __restrict__ bsum,
                         const int* __restrict__ cnt, float* __restrict__ dinv,
                         int* __restrict__ partial) {
    int i = blockIdx.x * 256 + threadIdx.x;
    if (i < NN) {
        int v = rp[i] + bsum[i >> 10];
        rp[i] = v;
        dinv[i] = rsqrtf((float)(cnt[i] + 1));
        int p = i / RNG, il = i - p * RNG;
        int* q = partial + (p * SSL) * RNG + il;
        int run = v;
#pragma unroll
        for (int s = 0; s < SSL; ++s) { int t = q[s * RNG]; q[s * RNG] = run; run += t; }
    }
    if (i == 0) rp[NN] = NE;
}

__global__ __launch_bounds__(256) void k_fillb(const int* __restrict__ dst32,
                                               const int* __restrict__ src32,
                                               const int* __restrict__ offs,
                                               int* __restrict__ col) {
    __shared__ int h[RNG];
    int p = blockIdx.x >> 5, s = blockIdx.x & 31;
    int t = threadIdx.x;
    const int* o = offs + blockIdx.x * RNG;
    for (int i = t * 4; i < RNG; i += 1024) *(int4*)(h + i) = *(const int4*)(o + i);
    __syncthreads();
    int base = s * NES;
    int lo = p * RNG;
    int nfull = NES & ~1023;
    for (int k = t * 4; k < nfull; k += 1024) {
        int4 d4 = *(const int4*)(dst32 + base + k);
        int4 s4 = *(const int4*)(src32 + base + k);
        int a;
        a = d4.x - lo; if ((unsigned)a < RNG) col[atomicAdd(&h[a], 1)] = s4.x;
        a = d4.y - lo; if ((unsigned)a < RNG) col[atomicAdd(&h[a], 1)] = s4.y;
        a = d4.z - lo; if ((unsigned)a < RNG) col[atomicAdd(&h[a], 1)] = s4.z;
        a = d4.w - lo; if ((unsigned)a < RNG) col[atomicAdd(&h[a], 1)] = s4.w;
    }
    for (int k = nfull + t; k < NES; k += 256) {
        int a = dst32[base + k] - lo;
        if ((unsigned)a < RNG) col[atomicAdd(&h[a], 1)] = src32[base + k];
    }
}

// ---------------- Persistent-B GEMM (N=256 halves): C = epi(A @ Wt^T) ----------------
// out_fp8: write hs as fp8 e4m3 (for the gather kernels); else bf16.

#define GLL(g, l) __builtin_amdgcn_global_load_lds( \
    (const __attribute__((address_space(1))) unsigned int*)(g), \
    (__attribute__((address_space(3))) unsigned int*)(l), 16, 0, 0)

#define NT128 ((NN + 127) / 128)
#define NT256 ((NN + 255) / 256)

__global__ __launch_bounds__(256) void k_gemmP(const u16* __restrict__ A,
                                               const u16* __restrict__ Wt,
                                               const float* __restrict__ dinv,
                                               const u16* __restrict__ bias,
                                               u16* __restrict__ C,
                                               int K, int out_fp8) {
    __shared__ __align__(16) u16 Bs[128 * 256];   // blocked [K/32][128][32]
    __shared__ __align__(16) u16 As[2 * 128 * 32];
    int t = threadIdx.x;
    int bn = blockIdx.y;
    int w = t >> 6, lane = t & 63;
    int wm = w >> 1, wn = w & 1;
    int lrow = lane & 15, lq = lane >> 4;
    int r0 = t >> 2;
    int seg = (t & 3) * 8;

    int rounds = K >> 4;
    for (int r = 0; r < rounds; ++r) {
        int d = r * 4096 + t * 16;
        int kt = d >> 13;
        int win = d & 8191;
        int row = win >> 6;
        int sg = (win & 63) >> 1;
        GLL(Wt + (size_t)(bn * 128 + row) * K + kt * 32 + sg, Bs + (d >> 1));
    }

    int nK = K >> 5;
    bool fuse = (bias != nullptr);
    float bcol[4];
#pragma unroll
    for (int j = 0; j < 4; ++j)
        bcol[j] = fuse ? bf2f(bias[bn * 128 + wn * 64 + j * 16 + lrow]) : 0.f;

    for (int tm = blockIdx.x; tm < NT128; tm += gridDim.x) {
        int rowBase = tm * 128;
        int ar0 = rowBase + r0;       if (ar0 > NN - 1) ar0 = NN - 1;
        int ar1 = rowBase + 64 + r0;  if (ar1 > NN - 1) ar1 = NN - 1;
        const u16* a0p = A + (size_t)ar0 * K + seg;
        const u16* a1p = A + (size_t)ar1 * K + seg;
        GLL(a0p, As + t * 8);
        GLL(a1p, As + 2048 + t * 8);

        f32x4 acc[4][4] = {};
        int cur = 0;
        for (int kt = 0; kt < nK; ++kt) {
            __syncthreads();
            if (kt + 1 < nK) {
                int nxt = cur ^ 1;
                GLL(a0p + (kt + 1) * 32, As + nxt * 4096 + t * 8);
                GLL(a1p + (kt + 1) * 32, As + nxt * 4096 + 2048 + t * 8);
            }
            const u16* ab = As + cur * 4096;
            const u16* bb = Bs + kt * 4096;
            s16x8 af[4], bf[4];
#pragma unroll
            for (int i = 0; i < 4; ++i)
                af[i] = *(const s16x8*)(ab + (wm * 64 + i * 16 + lrow) * 32 + lq * 8);
#pragma unroll
            for (int j = 0; j < 4; ++j)
                bf[j] = *(const s16x8*)(bb + (wn * 64 + j * 16 + lrow) * 32 + lq * 8);
#pragma unroll
            for (int i = 0; i < 4; ++i)
#pragma unroll
                for (int j = 0; j < 4; ++j)
                    acc[i][j] = __builtin_amdgcn_mfma_f32_16x16x32_bf16(af[i], bf[j], acc[i][j], 0, 0, 0);
            cur ^= 1;
        }

        u8* C8 = (u8*)C;
#pragma unroll
        for (int i = 0; i < 4; ++i) {
#pragma unroll
            for (int rr = 0; rr < 4; ++rr) {
                int row = rowBase + wm * 64 + i * 16 + lq * 4 + rr;
                if (row < NN) {
                    float d = dinv[row];
#pragma unroll
                    for (int j = 0; j < 4; ++j) {
                        int colg = bn * 128 + wn * 64 + j * 16 + lrow;
                        float v = fuse ? fmaxf(fmaf(d, acc[i][j][rr], bcol[j]), 0.f)
                                       : acc[i][j][rr] * d;
                        if (out_fp8) C8[(size_t)row * HIDDEN + colg] = f2fp8(v);
                        else         C[(size_t)row * HIDDEN + colg] = f2bf(v);
                    }
                }
            }
        }
        __syncthreads();
    }
}

// ---------------- Persistent-B GEMM conv5: 256-row x 64-col tiles, K=256 ----------------
__global__ __launch_bounds__(256) void k_gemmP64(const u16* __restrict__ A,
                                                 const u16* __restrict__ Wt,
                                                 const float* __restrict__ dinv,
                                                 u16* __restrict__ C) {
    const int K = 256;
    __shared__ __align__(16) u16 Bs[64 * 256];
    __shared__ __align__(16) u16 As[2 * 256 * 32];
    int t = threadIdx.x;
    int w = t >> 6, lane = t & 63;
    int lrow = lane & 15, lq = lane >> 4;
    int seg = (t & 3) * 8;
    int rr0 = t >> 2;

    for (int r = 0; r < 8; ++r)
        GLL(Wt + (size_t)(t >> 2) * K + r * 32 + seg, Bs + r * 2048 + t * 8);

    for (int tm = blockIdx.x; tm < NT256; tm += gridDim.x) {
        int rowBase = tm * 256;
        const u16* ap[4];
#pragma unroll
        for (int c = 0; c < 4; ++c) {
            int ar = rowBase + c * 64 + rr0;
            if (ar > NN - 1) ar = NN - 1;
            ap[c] = A + (size_t)ar * K + seg;
        }
#pragma unroll
        for (int c = 0; c < 4; ++c) GLL(ap[c], As + c * 2048 + t * 8);

        f32x4 acc[4][4] = {};
        int cur = 0;
        for (int kt = 0; kt < 8; ++kt) {
            __syncthreads();
            if (kt + 1 < 8) {
                int nxt = cur ^ 1;
#pragma unroll
                for (int c = 0; c < 4; ++c)
                    GLL(ap[c] + (kt + 1) * 32, As + nxt * 8192 + c * 2048 + t * 8);
            }
            const u16* ab = As + cur * 8192;
            const u16* bb = Bs + kt * 2048;
            s16x8 af[4], bf[4];
#pragma unroll
            for (int i = 0; i < 4; ++i)
                af[i] = *(const s16x8*)(ab + (w * 64 + i * 16 + lrow) * 32 + lq * 8);
#pragma unroll
            for (int j = 0; j < 4; ++j)
                bf[j] = *(const s16x8*)(bb + (j * 16 + lrow) * 32 + lq * 8);
#pragma unroll
            for (int i = 0; i < 4; ++i)
#pragma unroll
                for (int j = 0; j < 4; ++j)
                    acc[i][j] = __builtin_amdgcn_mfma_f32_16x16x32_bf16(af[i], bf[j], acc[i][j], 0, 0, 0);
            cur ^= 1;
        }

#pragma unroll
        for (int i = 0; i < 4; ++i) {
#pragma unroll
            for (int rr = 0; rr < 4; ++rr) {
                int row = rowBase + w * 64 + i * 16 + lq * 4 + rr;
                if (row < NN) {
                    float d = dinv[row];
#pragma unroll
                    for (int j = 0; j < 4; ++j) {
                        int colg = j * 16 + lrow;
                        C[(size_t)row * 64 + colg] = f2bf(acc[i][j][rr] * d);
                    }
                }
            }
        }
        __syncthreads();
    }
}

// ---------------- aggregation F=256 over fp8 hs (convs 2-4) ----------------
// one wave per row; half-wave per edge (256 B fp8 row), 4x unroll; HW fp8 decode.

__global__ __launch_bounds__(256) void k_agg8(const u8* __restrict__ hs,
                                              const int* __restrict__ rp,
                                              const int* __restrict__ col,
                                              const float* __restrict__ dinv,
                                              const u16* __restrict__ bias,
                                              u16* __restrict__ out) {
    int row = blockIdx.x * 4 + (threadIdx.x >> 6);
    if (row >= NN) return;
    int lane = threadIdx.x & 63;
    int half = lane >> 5;
    int fb = (lane & 31) * 8;          // feature index, 8 per lane
    float a[8] = {0.f, 0.f, 0.f, 0.f, 0.f, 0.f, 0.f, 0.f};
    auto accum = [&](uint2 v) {
        f32x2 x0 = __builtin_amdgcn_cvt_pk_f32_fp8(v.x, false);
        f32x2 x1 = __builtin_amdgcn_cvt_pk_f32_fp8(v.x, true);
        f32x2 x2 = __builtin_amdgcn_cvt_pk_f32_fp8(v.y, false);
        f32x2 x3 = __builtin_amdgcn_cvt_pk_f32_fp8(v.y, true);
        a[0] += x0.x; a[1] += x0.y; a[2] += x1.x; a[3] += x1.y;
        a[4] += x2.x; a[5] += x2.y; a[6] += x3.x; a[7] += x3.y;
    };
    if (half == 0) accum(*(const uint2*)(hs + (size_t)row * HIDDEN + fb));
    int p = rp[row] + half, p1 = rp[row + 1];
    for (; p + 6 < p1; p += 8) {
        int s0 = col[p], s1 = col[p + 2], s2 = col[p + 4], s3 = col[p + 6];
        uint2 v0 = *(const uint2*)(hs + (size_t)s0 * HIDDEN + fb);
        uint2 v1 = *(const uint2*)(hs + (size_t)s1 * HIDDEN + fb);
        uint2 v2 = *(const uint2*)(hs + (size_t)s2 * HIDDEN + fb);
        uint2 v3 = *(const uint2*)(hs + (size_t)s3 * HIDDEN + fb);
        accum(v0);
        accum(v1);
        accum(v2);
        accum(v3);
    }
    for (; p < p1; p += 2) {
        int s = col[p];
        accum(*(const uint2*)(hs + (size_t)s * HIDDEN + fb));
    }
#pragma unroll
    for (int i = 0; i < 8; ++i) a[i] += __shfl_xor(a[i], 32);
    if (half == 0) {
        float d = dinv[row];
        uint4 bv = *(const uint4*)(bias + fb);
        float r0 = fmaxf(fmaf(d, a[0], bf2f((u16)(bv.x & 0xffff))), 0.f);
        float r1 = fmaxf(fmaf(d, a[1], bf2f((u16)(bv.x >> 16))), 0.f);
        float r2 = fmaxf(fmaf(d, a[2], bf2f((u16)(bv.y & 0xffff))), 0.f);
        float r3 = fmaxf(fmaf(d, a[3], bf2f((u16)(bv.y >> 16))), 0.f);
        float r4 = fmaxf(fmaf(d, a[4], bf2f((u16)(bv.z & 0xffff))), 0.f);
        float r5 = fmaxf(fmaf(d, a[5], bf2f((u16)(bv.z >> 16))), 0.f);
        float r6 = fmaxf(fmaf(d, a[6], bf2f((u16)(bv.w & 0xffff))), 0.f);
        float r7 = fmaxf(fmaf(d, a[7], bf2f((u16)(bv.w >> 16))), 0.f);
        uint4 o;
        o.x = (uint32_t)f2bf(r0) | ((uint32_t)f2bf(r1) << 16);
        o.y = (uint32_t)f2bf(r2) | ((uint32_t)f2bf(r3) << 16);
        o.z = (uint32_t)f2bf(r4) | ((uint32_t)f2bf(r5) << 16);
        o.w = (uint32_t)f2bf(r6) | ((uint32_t)f2bf(r7) << 16);
        *(uint4*)(out + (size_t)row * HIDDEN + fb) = o;
    }
}

// ---------------- conv1 pre-aggregation on prescaled x (128 features, bf16) ----------------
__global__ __launch_bounds__(256) void k_aggx(const u16* __restrict__ xb,
                                              const int* __restrict__ rp,
                                              const int* __restrict__ col,
                                              u16* __restrict__ out) {
    int row = blockIdx.x * 4 + (threadIdx.x >> 6);
    if (row >= NN) return;
    int lane = threadIdx.x & 63;
    int half = lane >> 5;
    int fb = (lane & 31) * 4;
    float a0 = 0.f, a1 = 0.f, a2 = 0.f, a3 = 0.f;
    if (half == 0) {
        uint2 v = *(const uint2*)(xb + (size_t)row * FIN + fb);
        a0 = bf2f((u16)(v.x & 0xffff)); a1 = bf2f((u16)(v.x >> 16));
        a2 = bf2f((u16)(v.y & 0xffff)); a3 = bf2f((u16)(v.y >> 16));
    }
    int p = rp[row] + half, p1 = rp[row + 1];
    for (; p + 6 < p1; p += 8) {
        int s0 = col[p], s1 = col[p + 2], s2 = col[p + 4], s3 = col[p + 6];
        uint2 v0 = *(const uint2*)(xb + (size_t)s0 * FIN + fb);
        uint2 v1 = *(const uint2*)(xb + (size_t)s1 * FIN + fb);
        uint2 v2 = *(const uint2*)(xb + (size_t)s2 * FIN + fb);
        uint2 v3 = *(const uint2*)(xb + (size_t)s3 * FIN + fb);
        a0 += bf2f((u16)(v0.x & 0xffff)) + bf2f((u16)(v1.x & 0xffff))
            + bf2f((u16)(v2.x & 0xffff)) + bf2f((u16)(v3.x & 0xffff));
        a1 += bf2f((u16)(v0.x >> 16)) + bf2f((u16)(v1.x >> 16))
            + bf2f((u16)(v2.x >> 16)) + bf2f((u16)(v3.x >> 16));
        a2 += bf2f((u16)(v0.y & 0xffff)) + bf2f((u16)(v1.y & 0xffff))
            + bf2f((u16)(v2.y & 0xffff)) + bf2f((u16)(v3.y & 0xffff));
        a3 += bf2f((u16)(v0.y >> 16)) + bf2f((u16)(v1.y >> 16))
            + bf2f((u16)(v2.y >> 16)) + bf2f((u16)(v3.y >> 16));
    }
    for (; p < p1; p += 2) {
        int s = col[p];
        uint2 v = *(const uint2*)(xb + (size_t)s * FIN + fb);
        a0 += bf2f((u16)(v.x & 0xffff)); a1 += bf2f((u16)(v.x >> 16));
        a2 += bf2f((u16)(v.y & 0xffff)); a3 += bf2f((u16)(v.y >> 16));
    }
    a0 += __shfl_xor(a0, 32); a1 += __shfl_xor(a1, 32);
    a2 += __shfl_xor(a2, 32); a3 += __shfl_xor(a3, 32);
    if (half == 0) {
        uint2 o;
        o.x = (uint32_t)f2bf(a0) | ((uint32_t)f2bf(a1) << 16);
        o.y = (uint32_t)f2bf(a2) | ((uint32_t)f2bf(a3) << 16);
        *(uint2*)(out + (size_t)row * FIN + fb) = o;
    }
}

// ---------------- last layer: hs padded to 64 cols (bf16); agg + bias + log_softmax ----------------
__global__ __launch_bounds__(256) void k_agg5(const u16* __restrict__ hs,
                                              const int* __restrict__ rp,
                                              const int* __restrict__ col,
                                              const float* __restrict__ dinv,
                                              const u16* __restrict__ bias,
                                              void* __restrict__ out,
                                              const int* __restrict__ flags) {
    int row = blockIdx.x * 4 + (threadIdx.x >> 6);
    if (row >= NN) return;
    int lane = threadIdx.x & 63;
    int half = lane >> 5;
    int cl2 = lane & 31;
    float a0 = 0.f, a1 = 0.f;
    if (half == 0) {
        uint32_t v = *(const uint32_t*)(hs + (size_t)row * 64 + 2 * cl2);
        a0 = bf2f((u16)(v & 0xffff)); a1 = bf2f((u16)(v >> 16));
    }
    int p = rp[row] + half, p1 = rp[row + 1];
    for (; p + 6 < p1; p += 8) {
        int s0 = col[p], s1 = col[p + 2], s2 = col[p + 4], s3 = col[p + 6];
        uint32_t v0 = *(const uint32_t*)(hs + (size_t)s0 * 64 + 2 * cl2);
        uint32_t v1 = *(const uint32_t*)(hs + (size_t)s1 * 64 + 2 * cl2);
        uint32_t v2 = *(const uint32_t*)(hs + (size_t)s2 * 64 + 2 * cl2);
        uint32_t v3 = *(const uint32_t*)(hs + (size_t)s3 * 64 + 2 * cl2);
        a0 += bf2f((u16)(v0 & 0xffff)) + bf2f((u16)(v1 & 0xffff))
            + bf2f((u16)(v2 & 0xffff)) + bf2f((u16)(v3 & 0xffff));
        a1 += bf2f((u16)(v0 >> 16)) + bf2f((u16)(v1 >> 16))
            + bf2f((u16)(v2 >> 16)) + bf2f((u16)(v3 >> 16));
    }
    for (; p < p1; p += 2) {
        int s = col[p];
        uint32_t v = *(const uint32_t*)(hs + (size_t)s * 64 + 2 * cl2);
        a0 += bf2f((u16)(v & 0xffff));
        a1 += bf2f((u16)(v >> 16));
    }
    a0 += __shfl_xor(a0, 32);
    a1 += __shfl_xor(a1, 32);
    bool act = cl2 < (NCLS / 2);
    float d = dinv[row];
    uint32_t bv = *(const uint32_t*)(bias + 2 * cl2);
    float l0 = act ? fmaf(d, a0, bf2f((u16)(bv & 0xffff))) : -1e30f;
    float l1 = act ? fmaf(d, a1, bf2f((u16)(bv >> 16))) : -1e30f;
    float m = fmaxf(l0, l1);
#pragma unroll
    for (int off = 16; off > 0; off >>= 1) m = fmaxf(m, __shfl_xor(m, off));
    float e = act ? (__expf(l0 - m) + __expf(l1 - m)) : 0.f;
    float ss = e;
#pragma unroll
    for (int off = 16; off > 0; off >>= 1) ss += __shfl_xor(ss, off);
    if (act && half == 0) {
        float lg = __logf(ss);
        float r0 = l0 - m - lg, r1 = l1 - m - lg;
        if (flags[0]) {
            float* o = (float*)out + (size_t)row * NCLS + 2 * cl2;
            o[0] = r0; o[1] = r1;
        } else {
            uint32_t pk = (uint32_t)f2bf(r0) | ((uint32_t)f2bf(r1) << 16);
            *(uint32_t*)((u16*)out + (size_t)row * NCLS + 2 * cl2) = pk;
        }
    }
}

// ---------------- launch ----------------

extern "C" void kernel_launch(void* const* d_in, const int* in_sizes, int n_in,
                              void* d_out, int out_size, void* d_ws, size_t ws_size,
                              hipStream_t stream) {
    const void* x  = d_in[0];
    const int* ei  = (const int*)d_in[1];
    const void* W1 = d_in[2];
    const void* b1 = d_in[3];
    const void* W2 = d_in[4];
    const void* b2 = d_in[5];
    const void* W3 = d_in[6];
    const void* b3 = d_in[7];
    const void* W4 = d_in[8];
    const void* b4 = d_in[9];

    char* p = (char*)d_ws;
    auto alloc = [&](size_t b) -> char* {
        char* r = p;
        p += (b + 255) & ~(size_t)255;
        return r;
    };
    int*   flags = (int*)alloc(256);
    int*   cnt  = (int*)alloc((size_t)NN * 4);
    float* dinv = (float*)alloc((size_t)NN * 4);
    int*   rp   = (int*)alloc((size_t)(NN + 1) * 4);
    int*   col  = (int*)alloc((size_t)NE * 4);
    int*   bsum = (int*)alloc(4096);
    u16* xb  = (u16*)alloc((size_t)NN * FIN * 2);
    u16* W1t = (u16*)alloc((size_t)256 * 128 * 2);
    u16* W2t = (u16*)alloc((size_t)256 * 256 * 2);
    u16* W3t = (u16*)alloc((size_t)256 * 256 * 2);
    u16* W4t = (u16*)alloc((size_t)64 * 256 * 2);
    u16* bb1 = (u16*)alloc(512);
    u16* bb2 = (u16*)alloc(512);
    u16* bb3 = (u16*)alloc(512);
    u16* bb4 = (u16*)alloc(128);
    u16* bufA = (u16*)alloc((size_t)NN * HIDDEN * 2);
    u16* bufB = (u16*)alloc((size_t)NN * HIDDEN * 2);

    // CSR-build scratch aliased into conv buffers (dead before conv use)
    int* dst32   = (int*)bufA;                    // 6.4 MB
    int* src32   = dst32 + NE;                    // 6.4 MB
    int* partial = (int*)bufB;                    // 12.8 MB

    k_detect<<<1, 256, 0, stream>>>((const u16*)x, ei, flags);
    k_compact<<<(NE + 255) / 256, 256, 0, stream>>>(ei, dst32, src32, flags);

    // CSR build (atomic-free at device scope, i32 streams)
    k_histb<<<PRNG * SSL, 256, 0, stream>>>(dst32, partial);
    k_scan1<<<(NN + 1023) / 1024, 256, 0, stream>>>(partial, cnt, rp, bsum);
    k_scan2<<<1, 64, 0, stream>>>(bsum, (NN + 1023) / 1024);
    k_scan3o<<<(NN + 255) / 256, 256, 0, stream>>>(rp, bsum, cnt, dinv, partial);
    k_fillb<<<PRNG * SSL, 256, 0, stream>>>(dst32, src32, partial, col);

    // weights/bias transpose + x convert (prescaled by dinv), one launch
    k_trans_cvt<<<705 + (NN * FIN + 255) / 256, 256, 0, stream>>>(
        W1, W2, W3, W4, W1t, W2t, W3t, W4t,
        b1, b2, b3, b4, bb1, bb2, bb3, bb4, x, dinv, xb, flags);

    dim3 gP(256, 2);
    dim3 aggGrid((NN + 3) / 4);

    // conv1 (aggregate-then-transform): y = A_hat_scaled @ xb; h1 = relu(dinv*(y W1) + b1)
    k_aggx<<<aggGrid, 256, 0, stream>>>(xb, rp, col, bufB);
    k_gemmP<<<gP, 256, 0, stream>>>(bufB, W1t, dinv, bb1, bufA, 128, 0);
    // conv2: @ W2 -> hs in fp8, gather in fp8
    k_gemmP<<<gP, 256, 0, stream>>>(bufA, W2t, dinv, nullptr, bufB, 256, 1);
    k_agg8<<<aggGrid, 256, 0, stream>>>((const u8*)bufB, rp, col, dinv, bb2, bufA);
    // conv3: @ W2 (reused)
    k_gemmP<<<gP, 256, 0, stream>>>(bufA, W2t, dinv, nullptr, bufB, 256, 1);
    k_agg8<<<aggGrid, 256, 0, stream>>>((const u8*)bufB, rp, col, dinv, bb2, bufA);
    // conv4: @ W3
    k_gemmP<<<gP, 256, 0, stream>>>(bufA, W3t, dinv, nullptr, bufB, 256, 1);
    k_agg8<<<aggGrid, 256, 0, stream>>>((const u8*)bufB, rp, col, dinv, bb3, bufA);
    // conv5: @ W4 (persistent-B, padded to 64 cols, bf16) + fused log_softmax
    k_gemmP64<<<256, 256, 0, stream>>>(bufA, W4t, dinv, bufB);
    k_agg5<<<aggGrid, 256, 0, stream>>>(bufB, rp, col, dinv, bb4, d_out, flags);
}